// Round 11
// baseline (764.779 us; speedup 1.0000x reference)
//
#include <hip/hip_runtime.h>

#define NH 96
#define NH2 192

typedef __attribute__((ext_vector_type(8))) short short8;
typedef __attribute__((ext_vector_type(4))) float f32x4;

__device__ __forceinline__ unsigned short f2b(float f) {
  unsigned u = __float_as_uint(f);
  unsigned r = (u + 0x7FFFu + ((u >> 16) & 1u)) >> 16;
  return (unsigned short)r;
}
__device__ __forceinline__ float blo(unsigned w) { return __uint_as_float(w << 16); }
__device__ __forceinline__ float bhi(unsigned w) { return __uint_as_float(w & 0xFFFF0000u); }
__device__ __forceinline__ float b2f(short v) { return __uint_as_float(((unsigned)(unsigned short)v) << 16); }

__device__ __forceinline__ unsigned cvt_pk(float lo, float hi) {
  unsigned r;
  asm("v_cvt_pk_bf16_f32 %0, %1, %2" : "=v"(r) : "v"(lo), "v"(hi));
  return r;
}

__device__ __forceinline__ short8 u4_to_s8(int a, int b, int c, int d) {
  union { int u[4]; short8 s; } x;
  x.u[0] = a; x.u[1] = b; x.u[2] = c; x.u[3] = d;
  return x.s;
}

#define MFMA(a, b, c) __builtin_amdgcn_mfma_f32_16x16x32_bf16((a), (b), (c), 0, 0, 0)
#define WFRAG(p, idx) (*(const short8*)((p) + ((idx) << 9) + (l << 3)))

// block-cooperative weight staging: global -> LDS, 16B per thread per iter
__device__ __forceinline__ void stage(unsigned short* dst, const unsigned short* src, int nshorts, int tid) {
  const uint4* s = (const uint4*)src;
  uint4* d = (uint4*)dst;
  int nv = nshorts >> 3;
  for (int i = tid; i < nv; i += 256) d[i] = s[i];
}

// cross-g exchange: target lane (c,g) builds B-fragment elems H[c][kf*32+g*8+j]
__device__ __forceinline__ short8 xchg(unsigned p0lo, unsigned p0hi, unsigned p1lo, unsigned p1hi,
                                       int srcA, int srcB, int hi) {
  int a0 = __shfl((int)p0lo, srcA), a1 = __shfl((int)p0hi, srcA);
  int c0 = __shfl((int)p1lo, srcA), c1 = __shfl((int)p1hi, srcA);
  int b0 = __shfl((int)p0lo, srcB), b1 = __shfl((int)p0hi, srcB);
  int d0 = __shfl((int)p1lo, srcB), d1 = __shfl((int)p1hi, srcB);
  return u4_to_s8(hi ? c0 : a0, hi ? c1 : a1, hi ? d0 : b0, hi ? d1 : b1);
}

// ---------------- CSR build ----------------

__global__ void k_count(const int* __restrict__ dst1, const int* __restrict__ dst2,
                        int* __restrict__ cnt1, int* __restrict__ cnt2, int E) {
  int e = blockIdx.x * blockDim.x + threadIdx.x;
  if (e < E) {
    atomicAdd(&cnt1[dst1[e]], 1);
    atomicAdd(&cnt2[dst2[e]], 1);
  }
}

// writes rp AND initializes cur = rp (folds the old d2d memcpy in)
__global__ __launch_bounds__(1024) void k_scan(const int* __restrict__ cnt, int* __restrict__ rp,
                                               int* __restrict__ cur, int n) {
  __shared__ int s[1024];
  int tid = threadIdx.x;
  int chunk = (n + 1023) >> 10;
  int beg = tid * chunk;
  int end = min(beg + chunk, n);
  int sum = 0;
  for (int i = beg; i < end; ++i) sum += cnt[i];
  s[tid] = sum;
  __syncthreads();
  for (int off = 1; off < 1024; off <<= 1) {
    int v = (tid >= off) ? s[tid - off] : 0;
    __syncthreads();
    s[tid] += v;
    __syncthreads();
  }
  int excl = (tid == 0) ? 0 : s[tid - 1];
  for (int i = beg; i < end; ++i) { rp[i] = excl; cur[i] = excl; excl += cnt[i]; }
  if (tid == 1023) rp[n] = s[1023];
}

// dst-partitioned scatter: partition p = blockIdx.x & 7 handles dst in [p*psize, (p+1)*psize).
// With round-robin workgroup->XCD dispatch, each CSR region is written by one XCD ->
// full 64B lines accumulate in that XCD's L2 and write back once (not per-edge).
// Correctness does not depend on the mapping. cur pre-initialized to rp.
__global__ void k_scatter(const int* __restrict__ d1, const int* __restrict__ s1, const float* __restrict__ v1,
                          int* __restrict__ cur1, int2* __restrict__ c1sv,
                          const int* __restrict__ s2, const int* __restrict__ d2,
                          int* __restrict__ cur2, int* __restrict__ c2s, int E, int psize) {
  int p = blockIdx.x & 7;
  int e = (blockIdx.x >> 3) * blockDim.x + threadIdx.x;
  if (e >= E) return;
  int lo = p * psize, hi = lo + psize;
  int d = d1[e];
  if (d >= lo && d < hi) {
    int pos = atomicAdd(&cur1[d], 1);
    c1sv[pos] = make_int2(s1[e], __float_as_int(v1[e]));
  }
  int dd = d2[e];
  if (dd >= lo && dd < hi) {
    int pos = atomicAdd(&cur2[dd], 1);
    c2s[pos] = s2[e];
  }
}

// ---------------- weight prep ----------------

__global__ void k_cvtgw(const float* __restrict__ W, unsigned short* __restrict__ Wb, int total) {
  int i = (blockIdx.x * blockDim.x + threadIdx.x) * 4;
  if (i + 3 < total) {
    float4 v = *(const float4*)(W + i);
    ushort4 o;
    o.x = f2b(v.x); o.y = f2b(v.y); o.z = f2b(v.z); o.w = f2b(v.w);
    *(ushort4*)(Wb + i) = o;
  }
}

// Pack weights into MFMA fragment order: frag(t,kf) at [(t*NKF+kf)*512 + lane*8 + j],
// value = W[k][nn] with k = kf*32 + (lane>>4)*8 + j, nn = t*16 + (lane&15).
__global__ void k_packw(const float* __restrict__ Wl, const float* __restrict__ Wr,
                        const float* __restrict__ W1, const float* __restrict__ W2,
                        unsigned short* __restrict__ Wlp, unsigned short* __restrict__ Wrp,
                        unsigned short* __restrict__ W1p, unsigned short* __restrict__ W2p) {
  int t = blockIdx.x * blockDim.x + threadIdx.x;
  if (t < 129024) {
    bool isR = t >= 64512;
    int u = isR ? t - 64512 : t;
    int i = u / 9216, v = u % 9216;
    int tt = v / 1536, r = v % 1536;
    int kf = r / 512, w = r % 512, l = w >> 3, j = w & 7;
    int c = l & 15, g = l >> 4;
    int k = kf * 32 + g * 8 + j, nn = tt * 16 + c;
    float val = (isR ? Wr : Wl)[i * 9216 + k * 96 + nn];
    (isR ? Wrp : Wlp)[u] = f2b(val);
  } else if (t < 147456) {
    int u = t - 129024;
    int tt = u / 1536, r = u % 1536;
    int kf = r / 512, w = r % 512, l = w >> 3, j = w & 7;
    int c = l & 15, g = l >> 4;
    int k = kf * 32 + g * 8 + j, nn = tt * 16 + c;
    W1p[u] = f2b(W1[k * 192 + nn]);
  } else if (t < 184320) {
    int u = t - 147456;
    int tt = u / 3072, r = u % 3072;
    int kf = r / 512, w = r % 512, l = w >> 3, j = w & 7;
    int c = l & 15, g = l >> 4;
    int k = kf * 32 + g * 8 + j, nn = tt * 16 + c;
    W2p[u] = f2b(W2[k * 192 + nn]);
  }
}

// ---------------- gc1: weighted SPMM + bias + relu + l2norm (unroll-4) ----------------

__global__ __launch_bounds__(256) void k_gc1(const int* __restrict__ rp, const int2* __restrict__ cv,
                                             const unsigned short* __restrict__ Wb,
                                             const float* __restrict__ b, unsigned short* __restrict__ out, int n) {
  int gw = (blockIdx.x * 256 + threadIdx.x) >> 6;
  int l = threadIdx.x & 63;
  if (gw >= n) return;
  int s = rp[gw], e = rp[gw + 1];
  bool act = l < 48;
  float a0 = 0.f, a1 = 0.f, b0 = 0.f, b1 = 0.f, c0 = 0.f, c1 = 0.f, d0 = 0.f, d1 = 0.f;
  int i = s;
  for (; i + 3 < e; i += 4) {
    int2 q0 = cv[i], q1 = cv[i + 1], q2 = cv[i + 2], q3 = cv[i + 3];
    if (act) {
      unsigned w0 = *(const unsigned*)(Wb + (size_t)q0.x * NH + 2 * l);
      unsigned w1 = *(const unsigned*)(Wb + (size_t)q1.x * NH + 2 * l);
      unsigned w2 = *(const unsigned*)(Wb + (size_t)q2.x * NH + 2 * l);
      unsigned w3 = *(const unsigned*)(Wb + (size_t)q3.x * NH + 2 * l);
      float v0 = __int_as_float(q0.y), v1 = __int_as_float(q1.y);
      float v2 = __int_as_float(q2.y), v3 = __int_as_float(q3.y);
      a0 = fmaf(v0, blo(w0), a0); a1 = fmaf(v0, bhi(w0), a1);
      b0 = fmaf(v1, blo(w1), b0); b1 = fmaf(v1, bhi(w1), b1);
      c0 = fmaf(v2, blo(w2), c0); c1 = fmaf(v2, bhi(w2), c1);
      d0 = fmaf(v3, blo(w3), d0); d1 = fmaf(v3, bhi(w3), d1);
    }
  }
  for (; i < e; ++i) {
    int2 q0 = cv[i];
    if (act) {
      unsigned w0 = *(const unsigned*)(Wb + (size_t)q0.x * NH + 2 * l);
      float v0 = __int_as_float(q0.y);
      a0 = fmaf(v0, blo(w0), a0); a1 = fmaf(v0, bhi(w0), a1);
    }
  }
  a0 += b0 + c0 + d0; a1 += b1 + c1 + d1;
  if (act) {
    a0 = fmaxf(a0 + b[2 * l], 0.f);
    a1 = fmaxf(a1 + b[2 * l + 1], 0.f);
  } else { a0 = a1 = 0.f; }
  float ss = a0 * a0 + a1 * a1;
#pragma unroll
  for (int o = 1; o < 64; o <<= 1) ss += __shfl_xor(ss, o);
  float sc = 1.f / fmaxf(sqrtf(ss), 1e-12f);
  if (act) {
    unsigned pk = ((unsigned)f2b(a1 * sc) << 16) | f2b(a0 * sc);
    ((unsigned*)out)[(size_t)gw * 48 + l] = pk;
  }
}

// ---------------- mean aggregation (unroll-4) — shared branch input ----------------

__global__ __launch_bounds__(256) void k_agg(const int* __restrict__ rp, const int* __restrict__ csrc,
                                             const unsigned short* __restrict__ X,
                                             unsigned short* __restrict__ out, int n) {
  int gw = (blockIdx.x * 256 + threadIdx.x) >> 6;
  int l = threadIdx.x & 63;
  if (gw >= n) return;
  int s = rp[gw], e = rp[gw + 1];
  bool act = l < 48;
  float a0 = 0.f, a1 = 0.f, b0 = 0.f, b1 = 0.f, c0 = 0.f, c1 = 0.f, d0 = 0.f, d1 = 0.f;
  int i = s;
  for (; i + 3 < e; i += 4) {
    int s0 = csrc[i], s1 = csrc[i + 1], s2 = csrc[i + 2], s3 = csrc[i + 3];
    if (act) {
      unsigned w0 = *(const unsigned*)(X + (size_t)s0 * NH + 2 * l);
      unsigned w1 = *(const unsigned*)(X + (size_t)s1 * NH + 2 * l);
      unsigned w2 = *(const unsigned*)(X + (size_t)s2 * NH + 2 * l);
      unsigned w3 = *(const unsigned*)(X + (size_t)s3 * NH + 2 * l);
      a0 += blo(w0); a1 += bhi(w0);
      b0 += blo(w1); b1 += bhi(w1);
      c0 += blo(w2); c1 += bhi(w2);
      d0 += blo(w3); d1 += bhi(w3);
    }
  }
  for (; i < e; ++i) {
    int s0 = csrc[i];
    if (act) {
      unsigned w0 = *(const unsigned*)(X + (size_t)s0 * NH + 2 * l);
      a0 += blo(w0); a1 += bhi(w0);
    }
  }
  a0 += b0 + c0 + d0; a1 += b1 + c1 + d1;
  float inv = 1.f / fmaxf((float)(e - s), 1.f);
  if (act) {
    unsigned pk = ((unsigned)f2b(a1 * inv) << 16) | f2b(a0 * inv);
    ((unsigned*)out)[(size_t)gw * 48 + l] = pk;
  }
}

// ---------------- trunk fused agg+SAGE, T=1, LDS-staged weights ----------------

template <int EPI>
__global__ __launch_bounds__(256) void k_sageagg(const int* __restrict__ rp, const int* __restrict__ csrc,
                                                 const unsigned short* __restrict__ X,
                                                 const unsigned short* __restrict__ Wlp,
                                                 const unsigned short* __restrict__ Wrp,
                                                 const float* __restrict__ bias,
                                                 unsigned short* __restrict__ Y, int n) {
  __shared__ __align__(16) unsigned short sw[18432];
  int tid = threadIdx.x;
  int l = tid & 63;
  int m0 = (blockIdx.x * 4 + (tid >> 6)) * 16;
  int c = l & 15, g = l >> 4;

  stage(sw, Wlp, 9216, tid);
  stage(sw + 9216, Wrp, 9216, tid);
  __syncthreads();

  int nd = min(m0 + c, n - 1);
  int s = rp[nd], e = rp[nd + 1];

  float aa[3][8], bb[3][8];
#pragma unroll
  for (int kf = 0; kf < 3; ++kf)
#pragma unroll
    for (int j = 0; j < 8; ++j) { aa[kf][j] = 0.f; bb[kf][j] = 0.f; }

  const unsigned short* Xg = X + g * 8;
  int i = s;
  for (; i + 1 < e; i += 2) {
    const unsigned short* xr0 = Xg + (size_t)csrc[i] * NH;
    const unsigned short* xr1 = Xg + (size_t)csrc[i + 1] * NH;
    short8 a0 = *(const short8*)(xr0);
    short8 a1 = *(const short8*)(xr0 + 32);
    short8 a2 = *(const short8*)(xr0 + 64);
    short8 b0 = *(const short8*)(xr1);
    short8 b1 = *(const short8*)(xr1 + 32);
    short8 b2 = *(const short8*)(xr1 + 64);
#pragma unroll
    for (int j = 0; j < 8; ++j) {
      aa[0][j] += b2f(a0[j]); aa[1][j] += b2f(a1[j]); aa[2][j] += b2f(a2[j]);
      bb[0][j] += b2f(b0[j]); bb[1][j] += b2f(b1[j]); bb[2][j] += b2f(b2[j]);
    }
  }
  if (i < e) {
    const unsigned short* xr0 = Xg + (size_t)csrc[i] * NH;
    short8 a0 = *(const short8*)(xr0);
    short8 a1 = *(const short8*)(xr0 + 32);
    short8 a2 = *(const short8*)(xr0 + 64);
#pragma unroll
    for (int j = 0; j < 8; ++j) {
      aa[0][j] += b2f(a0[j]); aa[1][j] += b2f(a1[j]); aa[2][j] += b2f(a2[j]);
    }
  }
  float inv = 1.f / fmaxf((float)(e - s), 1.f);
  short8 af[3];
#pragma unroll
  for (int kf = 0; kf < 3; ++kf)
#pragma unroll
    for (int j = 0; j < 8; ++j) af[kf][j] = (short)f2b((aa[kf][j] + bb[kf][j]) * inv);

  size_t aoff = (size_t)nd * NH + g * 8;
  short8 xf[3];
#pragma unroll
  for (int kf = 0; kf < 3; ++kf) xf[kf] = *(const short8*)(X + aoff + kf * 32);

  f32x4 acc[6];
#pragma unroll
  for (int t = 0; t < 6; ++t) acc[t] = (f32x4){0.f, 0.f, 0.f, 0.f};
#pragma unroll
  for (int kf = 0; kf < 3; ++kf) {
#pragma unroll
    for (int t = 0; t < 6; ++t) {
      short8 wlf = WFRAG(sw, t * 3 + kf);
      acc[t] = MFMA(wlf, af[kf], acc[t]);
    }
#pragma unroll
    for (int t = 0; t < 6; ++t) {
      short8 wrf = WFRAG(sw + 9216, t * 3 + kf);
      acc[t] = MFMA(wrf, xf[kf], acc[t]);
    }
  }

  float v[6][4];
  float ss = 0.f;
#pragma unroll
  for (int t = 0; t < 6; ++t) {
    float4 bv = *(const float4*)(bias + t * 16 + g * 4);
#pragma unroll
    for (int r = 0; r < 4; ++r) {
      float x = fmaxf(acc[t][r] + ((const float*)&bv)[r], 0.f);
      v[t][r] = x;
      ss = fmaf(x, x, ss);
    }
  }
  if (EPI == 0) {
    ss += __shfl_xor(ss, 16);
    ss += __shfl_xor(ss, 32);
    float sc = 1.f / fmaxf(sqrtf(ss), 1e-12f);
#pragma unroll
    for (int t = 0; t < 6; ++t)
#pragma unroll
      for (int r = 0; r < 4; ++r) v[t][r] *= sc;
  }
  if (m0 + c < n) {
    unsigned short* yr = Y + (size_t)(m0 + c) * NH;
#pragma unroll
    for (int t = 0; t < 6; ++t)
      *(uint2*)(yr + t * 16 + g * 4) = make_uint2(cvt_pk(v[t][0], v[t][1]), cvt_pk(v[t][2], v[t][3]));
  }
}

// ---------------- fused 3-layer MLP, T=2, LDS-staged weights: score += mlp(X) ----------------

__global__ __launch_bounds__(256) void k_mlp(const unsigned short* __restrict__ X,
                                             const unsigned short* __restrict__ W1p, const float* __restrict__ b1,
                                             const unsigned short* __restrict__ W2p, const float* __restrict__ b2,
                                             const float* __restrict__ W3, const float* __restrict__ b3,
                                             float* __restrict__ score, int n) {
  __shared__ __align__(16) unsigned short sw[18432];
  int tid = threadIdx.x;
  int l = tid & 63;
  int m0 = (blockIdx.x * 4 + (tid >> 6)) * 32;
  int c = l & 15, g = l >> 4;
  int srcA = c + ((g & 1) << 5), srcB = srcA + 16, hi = g >> 1;
  int rA = min(m0 + c, n - 1), rB = min(m0 + 16 + c, n - 1);

  stage(sw, W1p, 18432, tid);

  short8 xf[2][3];
#pragma unroll
  for (int kf = 0; kf < 3; ++kf) {
    xf[0][kf] = *(const short8*)(X + (size_t)rA * NH + kf * 32 + g * 8);
    xf[1][kf] = *(const short8*)(X + (size_t)rB * NH + kf * 32 + g * 8);
  }
  __syncthreads();

  // MLP1, t-outer
  unsigned pk1[2][12][2];
#pragma unroll
  for (int t = 0; t < 12; ++t) {
    f32x4 a0 = (f32x4){0.f, 0.f, 0.f, 0.f};
    f32x4 a1 = (f32x4){0.f, 0.f, 0.f, 0.f};
#pragma unroll
    for (int kf = 0; kf < 3; ++kf) {
      short8 wf = WFRAG(sw, t * 3 + kf);
      a0 = MFMA(wf, xf[0][kf], a0);
      a1 = MFMA(wf, xf[1][kf], a1);
    }
    float4 bv = *(const float4*)(b1 + t * 16 + g * 4);
    pk1[0][t][0] = cvt_pk(fmaxf(a0[0] + bv.x, 0.f), fmaxf(a0[1] + bv.y, 0.f));
    pk1[0][t][1] = cvt_pk(fmaxf(a0[2] + bv.z, 0.f), fmaxf(a0[3] + bv.w, 0.f));
    pk1[1][t][0] = cvt_pk(fmaxf(a1[0] + bv.x, 0.f), fmaxf(a1[1] + bv.y, 0.f));
    pk1[1][t][1] = cvt_pk(fmaxf(a1[2] + bv.z, 0.f), fmaxf(a1[3] + bv.w, 0.f));
  }

  short8 af2[2][6];
#pragma unroll
  for (int kf = 0; kf < 6; ++kf) {
    af2[0][kf] = xchg(pk1[0][2 * kf][0], pk1[0][2 * kf][1], pk1[0][2 * kf + 1][0], pk1[0][2 * kf + 1][1], srcA, srcB, hi);
    af2[1][kf] = xchg(pk1[1][2 * kf][0], pk1[1][2 * kf][1], pk1[1][2 * kf + 1][0], pk1[1][2 * kf + 1][1], srcA, srcB, hi);
  }

  float sv0 = 0.f, sv1 = 0.f;
#pragma unroll
  for (int h = 0; h < 2; ++h) {
    __syncthreads();
    stage(sw, W2p + h * 18432, 18432, tid);
    __syncthreads();
#pragma unroll
    for (int tt = 0; tt < 6; ++tt) {
      int t = h * 6 + tt;
      f32x4 a0 = (f32x4){0.f, 0.f, 0.f, 0.f};
      f32x4 a1 = (f32x4){0.f, 0.f, 0.f, 0.f};
#pragma unroll
      for (int kf = 0; kf < 6; ++kf) {
        short8 wf = WFRAG(sw, tt * 6 + kf);
        a0 = MFMA(wf, af2[0][kf], a0);
        a1 = MFMA(wf, af2[1][kf], a1);
      }
      float4 bv = *(const float4*)(b2 + t * 16 + g * 4);
      float4 wv3 = *(const float4*)(W3 + t * 16 + g * 4);
#pragma unroll
      for (int r = 0; r < 4; ++r) {
        sv0 = fmaf(fmaxf(a0[r] + ((const float*)&bv)[r], 0.f), ((const float*)&wv3)[r], sv0);
        sv1 = fmaf(fmaxf(a1[r] + ((const float*)&bv)[r], 0.f), ((const float*)&wv3)[r], sv1);
      }
    }
  }
  sv0 += __shfl_xor(sv0, 16); sv0 += __shfl_xor(sv0, 32);
  sv1 += __shfl_xor(sv1, 16); sv1 += __shfl_xor(sv1, 32);
  if (g == 0) {
    float b3v = b3[0];
    if (m0 + c < n) score[m0 + c] += sv0 + b3v;
    if (m0 + 16 + c < n) score[m0 + 16 + c] += sv1 + b3v;
  }
}

// ---------------- per-branch, T=2, LDS-staged weights ----------------

__global__ __launch_bounds__(256) void k_branch(const unsigned short* __restrict__ Ag,
                                                const unsigned short* __restrict__ X21,
                                                const unsigned short* __restrict__ Wlp,
                                                const unsigned short* __restrict__ Wrp,
                                                const float* __restrict__ sbl,
                                                const unsigned short* __restrict__ W1p, const float* __restrict__ b1,
                                                const unsigned short* __restrict__ W2p, const float* __restrict__ b2,
                                                const float* __restrict__ W3, const float* __restrict__ b3,
                                                unsigned short* __restrict__ Xb, float* __restrict__ score,
                                                int n, int gblk) {
  __shared__ __align__(16) unsigned short sw[18432];
  int bb = blockIdx.x / gblk;
  int blk = blockIdx.x - bb * gblk;
  int tid = threadIdx.x;
  int l = tid & 63;
  int m0 = (blk * 4 + (tid >> 6)) * 32;
  int c = l & 15, g = l >> 4;
  int srcA = c + ((g & 1) << 5), srcB = srcA + 16, hi = g >> 1;
  int rA = min(m0 + c, n - 1), rB = min(m0 + 16 + c, n - 1);
  size_t aoffA = (size_t)rA * NH + g * 8, aoffB = (size_t)rB * NH + g * 8;

  const float* bl = sbl + (size_t)bb * NH;

  stage(sw, Wlp + (size_t)bb * 9216, 9216, tid);
  stage(sw + 9216, Wrp + (size_t)bb * 9216, 9216, tid);

  short8 agf[2][3], xf[2][3];
#pragma unroll
  for (int kf = 0; kf < 3; ++kf) {
    agf[0][kf] = *(const short8*)(Ag + aoffA + kf * 32);
    agf[1][kf] = *(const short8*)(Ag + aoffB + kf * 32);
    xf[0][kf] = *(const short8*)(X21 + aoffA + kf * 32);
    xf[1][kf] = *(const short8*)(X21 + aoffB + kf * 32);
  }
  __syncthreads();

  // ---- SAGE, t-outer ----
  float v[2][6][4];
  float ss0 = 0.f, ss1 = 0.f;
#pragma unroll
  for (int t = 0; t < 6; ++t) {
    f32x4 a0 = (f32x4){0.f, 0.f, 0.f, 0.f};
    f32x4 a1 = (f32x4){0.f, 0.f, 0.f, 0.f};
#pragma unroll
    for (int kf = 0; kf < 3; ++kf) {
      short8 wlf = WFRAG(sw, t * 3 + kf);
      a0 = MFMA(wlf, agf[0][kf], a0);
      a1 = MFMA(wlf, agf[1][kf], a1);
      short8 wrf = WFRAG(sw + 9216, t * 3 + kf);
      a0 = MFMA(wrf, xf[0][kf], a0);
      a1 = MFMA(wrf, xf[1][kf], a1);
    }
    float4 bv = *(const float4*)(bl + t * 16 + g * 4);
#pragma unroll
    for (int r = 0; r < 4; ++r) {
      float x0 = fmaxf(a0[r] + ((const float*)&bv)[r], 0.f);
      float x1 = fmaxf(a1[r] + ((const float*)&bv)[r], 0.f);
      v[0][t][r] = x0; ss0 = fmaf(x0, x0, ss0);
      v[1][t][r] = x1; ss1 = fmaf(x1, x1, ss1);
    }
  }
  ss0 += __shfl_xor(ss0, 16); ss0 += __shfl_xor(ss0, 32);
  ss1 += __shfl_xor(ss1, 16); ss1 += __shfl_xor(ss1, 32);
  float sc0 = 1.f / fmaxf(sqrtf(ss0), 1e-12f);
  float sc1 = 1.f / fmaxf(sqrtf(ss1), 1e-12f);

  unsigned pk[2][6][2];
#pragma unroll
  for (int t = 0; t < 6; ++t) {
    pk[0][t][0] = cvt_pk(v[0][t][0] * sc0, v[0][t][1] * sc0);
    pk[0][t][1] = cvt_pk(v[0][t][2] * sc0, v[0][t][3] * sc0);
    pk[1][t][0] = cvt_pk(v[1][t][0] * sc1, v[1][t][1] * sc1);
    pk[1][t][1] = cvt_pk(v[1][t][2] * sc1, v[1][t][3] * sc1);
  }
  if (bb == 0) {
    if (m0 + c < n) {
      unsigned short* yr = Xb + (size_t)(m0 + c) * NH;
#pragma unroll
      for (int t = 0; t < 6; ++t) *(uint2*)(yr + t * 16 + g * 4) = make_uint2(pk[0][t][0], pk[0][t][1]);
    }
    if (m0 + 16 + c < n) {
      unsigned short* yr = Xb + (size_t)(m0 + 16 + c) * NH;
#pragma unroll
      for (int t = 0; t < 6; ++t) *(uint2*)(yr + t * 16 + g * 4) = make_uint2(pk[1][t][0], pk[1][t][1]);
    }
  }

  // ---- MLP1, t-outer ----
  __syncthreads();
  stage(sw, W1p, 18432, tid);
  short8 af1[2][3];
#pragma unroll
  for (int kf = 0; kf < 3; ++kf) {
    af1[0][kf] = xchg(pk[0][2 * kf][0], pk[0][2 * kf][1], pk[0][2 * kf + 1][0], pk[0][2 * kf + 1][1], srcA, srcB, hi);
    af1[1][kf] = xchg(pk[1][2 * kf][0], pk[1][2 * kf][1], pk[1][2 * kf + 1][0], pk[1][2 * kf + 1][1], srcA, srcB, hi);
  }
  __syncthreads();
  unsigned pk1[2][12][2];
#pragma unroll
  for (int t = 0; t < 12; ++t) {
    f32x4 a0 = (f32x4){0.f, 0.f, 0.f, 0.f};
    f32x4 a1 = (f32x4){0.f, 0.f, 0.f, 0.f};
#pragma unroll
    for (int kf = 0; kf < 3; ++kf) {
      short8 wf = WFRAG(sw, t * 3 + kf);
      a0 = MFMA(wf, af1[0][kf], a0);
      a1 = MFMA(wf, af1[1][kf], a1);
    }
    float4 bv = *(const float4*)(b1 + t * 16 + g * 4);
    pk1[0][t][0] = cvt_pk(fmaxf(a0[0] + bv.x, 0.f), fmaxf(a0[1] + bv.y, 0.f));
    pk1[0][t][1] = cvt_pk(fmaxf(a0[2] + bv.z, 0.f), fmaxf(a0[3] + bv.w, 0.f));
    pk1[1][t][0] = cvt_pk(fmaxf(a1[0] + bv.x, 0.f), fmaxf(a1[1] + bv.y, 0.f));
    pk1[1][t][1] = cvt_pk(fmaxf(a1[2] + bv.z, 0.f), fmaxf(a1[3] + bv.w, 0.f));
  }

  // ---- MLP2+3, t-outer, W2 staged in two halves ----
  short8 af2[2][6];
#pragma unroll
  for (int kf = 0; kf < 6; ++kf) {
    af2[0][kf] = xchg(pk1[0][2 * kf][0], pk1[0][2 * kf][1], pk1[0][2 * kf + 1][0], pk1[0][2 * kf + 1][1], srcA, srcB, hi);
    af2[1][kf] = xchg(pk1[1][2 * kf][0], pk1[1][2 * kf][1], pk1[1][2 * kf + 1][0], pk1[1][2 * kf + 1][1], srcA, srcB, hi);
  }
  float sv0 = 0.f, sv1 = 0.f;
#pragma unroll
  for (int h = 0; h < 2; ++h) {
    __syncthreads();
    stage(sw, W2p + h * 18432, 18432, tid);
    __syncthreads();
#pragma unroll
    for (int tt = 0; tt < 6; ++tt) {
      int t = h * 6 + tt;
      f32x4 a0 = (f32x4){0.f, 0.f, 0.f, 0.f};
      f32x4 a1 = (f32x4){0.f, 0.f, 0.f, 0.f};
#pragma unroll
      for (int kf = 0; kf < 6; ++kf) {
        short8 wf = WFRAG(sw, tt * 6 + kf);
        a0 = MFMA(wf, af2[0][kf], a0);
        a1 = MFMA(wf, af2[1][kf], a1);
      }
      float4 bv = *(const float4*)(b2 + t * 16 + g * 4);
      float4 wv3 = *(const float4*)(W3 + t * 16 + g * 4);
#pragma unroll
      for (int r = 0; r < 4; ++r) {
        sv0 = fmaf(fmaxf(a0[r] + ((const float*)&bv)[r], 0.f), ((const float*)&wv3)[r], sv0);
        sv1 = fmaf(fmaxf(a1[r] + ((const float*)&bv)[r], 0.f), ((const float*)&wv3)[r], sv1);
      }
    }
  }
  sv0 += __shfl_xor(sv0, 16); sv0 += __shfl_xor(sv0, 32);
  sv1 += __shfl_xor(sv1, 16); sv1 += __shfl_xor(sv1, 32);
  if (g == 0) {
    float b3v = b3[0];
    if (m0 + c < n) atomicAdd(&score[m0 + c], sv0 + b3v);
    if (m0 + 16 + c < n) atomicAdd(&score[m0 + 16 + c], sv1 + b3v);
  }
}

// ---------------- host ----------------

extern "C" void kernel_launch(void* const* d_in, const int* in_sizes, int n_in,
                              void* d_out, int out_size, void* d_ws, size_t ws_size,
                              hipStream_t stream) {
  const int* ei1 = (const int*)d_in[0];
  const float* ev1 = (const float*)d_in[1];
  const int* ei2 = (const int*)d_in[2];
  const float* gW = (const float*)d_in[3];
  const float* gb = (const float*)d_in[4];
  const float* sWl = (const float*)d_in[5];
  const float* sbl = (const float*)d_in[6];
  const float* sWr = (const float*)d_in[7];
  const float* W1 = (const float*)d_in[8];
  const float* b1 = (const float*)d_in[9];
  const float* W2 = (const float*)d_in[10];
  const float* b2 = (const float*)d_in[11];
  const float* W3 = (const float*)d_in[12];
  const float* b3 = (const float*)d_in[13];
  float* score = (float*)d_out;

  const int E = in_sizes[0] / 2;
  const int n = in_sizes[3] / NH;

  const int* d1 = ei1;      // edge_index1[0] = dst
  const int* s1 = ei1 + E;  // edge_index1[1] = src
  const int* s2 = ei2;      // edge_index2[0] = src
  const int* d2 = ei2 + E;  // edge_index2[1] = dst

  char* w = (char*)d_ws;
  auto alloc = [&](size_t bytes) {
    char* p = w;
    w += (bytes + 255) & ~(size_t)255;
    return p;
  };
  int* cnt1 = (int*)alloc((size_t)n * 4);
  int* cnt2 = (int*)alloc((size_t)n * 4);
  int* cur1 = (int*)alloc((size_t)n * 4);
  int* cur2 = (int*)alloc((size_t)n * 4);
  int* rp1 = (int*)alloc((size_t)(n + 1) * 4);
  int* rp2 = (int*)alloc((size_t)(n + 1) * 4);
  int2* c1sv = (int2*)alloc((size_t)E * 8);
  int* c2s = (int*)alloc((size_t)E * 4);
  unsigned short* gwb = (unsigned short*)alloc((size_t)n * NH * 2);
  unsigned short* wlp = (unsigned short*)alloc((size_t)7 * NH * NH * 2);
  unsigned short* wrp = (unsigned short*)alloc((size_t)7 * NH * NH * 2);
  unsigned short* w1p = (unsigned short*)alloc((size_t)NH * NH2 * 2);
  unsigned short* w2p = (unsigned short*)alloc((size_t)NH2 * NH2 * 2);
  unsigned short* x21 = (unsigned short*)alloc((size_t)n * NH * 2);
  unsigned short* Ag = (unsigned short*)alloc((size_t)n * NH * 2);
  unsigned short* xb = (unsigned short*)alloc((size_t)n * NH * 2);
  unsigned short* tb = (unsigned short*)alloc((size_t)n * NH * 2);

  // zero cnt1+cnt2 (contiguous region) + score
  size_t zbytes = (size_t)((char*)cur1 - (char*)cnt1) + (size_t)n * 4;
  hipMemsetAsync(cnt1, 0, zbytes, stream);
  hipMemsetAsync(score, 0, (size_t)n * 4, stream);

  int eb = (E + 255) / 256;
  int nb4 = (n + 3) / 4;          // wave-per-node kernels
  int sblk = (n + 63) / 64;       // T=1 staged agg+sage: 4 waves x 16 nodes
  int gblk = (n + 127) / 128;     // T=2 MFMA kernels: 4 waves x 32 nodes
  int psize = (n + 7) / 8;        // dst-partition size for scatter

  k_count<<<eb, 256, 0, stream>>>(d1, d2, cnt1, cnt2, E);
  k_scan<<<1, 1024, 0, stream>>>(cnt1, rp1, cur1, n);
  k_scan<<<1, 1024, 0, stream>>>(cnt2, rp2, cur2, n);
  k_scatter<<<eb * 8, 256, 0, stream>>>(d1, s1, ev1, cur1, c1sv, s2, d2, cur2, c2s, E, psize);

  k_cvtgw<<<(n * NH / 4 + 255) / 256, 256, 0, stream>>>(gW, gwb, n * NH);
  k_packw<<<720, 256, 0, stream>>>(sWl, sWr, W1, W2, wlp, wrp, w1p, w2p);

  // x2_1 = l2norm(relu(spmm(adj1, gc1_W) + gc1_b))
  k_gc1<<<nb4, 256, 0, stream>>>(rp1, c1sv, gwb, gb, x21, n);

  // score += mlp(x2_1)
  k_mlp<<<gblk, 256, 0, stream>>>(x21, w1p, b1, w2p, b2, W3, b3, score, n);

  // Ag = mean-agg(x2_1) — shared by all 6 score branches (incl. trunk layer 0)
  k_agg<<<nb4, 256, 0, stream>>>(rp2, c2s, x21, Ag, n);

  // 6 score branches (branch 0 emits xb = trunk layer-0 out)
  k_branch<<<6 * gblk, 256, 0, stream>>>(Ag, x21, wlp, wrp, sbl, w1p, b1, w2p, b2, W3, b3,
                                         xb, score, n, gblk);

  // trunk layers 1..5 (fused agg+sage, T=1 staged)
  unsigned short* xc = xb;
  unsigned short* xn = tb;
  for (int i = 1; i < 6; ++i) {
    k_sageagg<0><<<sblk, 256, 0, stream>>>(rp2, c2s, xc, wlp + (size_t)i * 9216,
                                           wrp + (size_t)i * 9216, sbl + (size_t)i * NH, xn, n);
    unsigned short* tmp = xc; xc = xn; xn = tmp;
  }

  // last layer: relu only, then final mlp
  k_sageagg<1><<<sblk, 256, 0, stream>>>(rp2, c2s, xc, wlp + (size_t)6 * 9216,
                                         wrp + (size_t)6 * 9216, sbl + (size_t)6 * NH, xn, n);
  k_mlp<<<gblk, 256, 0, stream>>>(xn, w1p, b1, w2p, b2, W3, b3, score, n);

  (void)n_in; (void)out_size; (void)ws_size;
}

// Round 12
// 559.773 us; speedup vs baseline: 1.3662x; 1.3662x over previous
//
#include <hip/hip_runtime.h>

#define NH 96
#define NH2 192

typedef __attribute__((ext_vector_type(8))) short short8;
typedef __attribute__((ext_vector_type(4))) float f32x4;

__device__ __forceinline__ unsigned short f2b(float f) {
  unsigned u = __float_as_uint(f);
  unsigned r = (u + 0x7FFFu + ((u >> 16) & 1u)) >> 16;
  return (unsigned short)r;
}
__device__ __forceinline__ float blo(unsigned w) { return __uint_as_float(w << 16); }
__device__ __forceinline__ float bhi(unsigned w) { return __uint_as_float(w & 0xFFFF0000u); }
__device__ __forceinline__ float b2f(short v) { return __uint_as_float(((unsigned)(unsigned short)v) << 16); }

__device__ __forceinline__ unsigned cvt_pk(float lo, float hi) {
  unsigned r;
  asm("v_cvt_pk_bf16_f32 %0, %1, %2" : "=v"(r) : "v"(lo), "v"(hi));
  return r;
}

__device__ __forceinline__ short8 u4_to_s8(int a, int b, int c, int d) {
  union { int u[4]; short8 s; } x;
  x.u[0] = a; x.u[1] = b; x.u[2] = c; x.u[3] = d;
  return x.s;
}

#define MFMA(a, b, c) __builtin_amdgcn_mfma_f32_16x16x32_bf16((a), (b), (c), 0, 0, 0)
#define WFRAG(p, idx) (*(const short8*)((p) + ((idx) << 9) + (l << 3)))

// block-cooperative weight staging: global -> LDS, 16B per thread per iter
__device__ __forceinline__ void stage(unsigned short* dst, const unsigned short* src, int nshorts, int tid) {
  const uint4* s = (const uint4*)src;
  uint4* d = (uint4*)dst;
  int nv = nshorts >> 3;
  for (int i = tid; i < nv; i += 256) d[i] = s[i];
}

// cross-g exchange: target lane (c,g) builds B-fragment elems H[c][kf*32+g*8+j]
__device__ __forceinline__ short8 xchg(unsigned p0lo, unsigned p0hi, unsigned p1lo, unsigned p1hi,
                                       int srcA, int srcB, int hi) {
  int a0 = __shfl((int)p0lo, srcA), a1 = __shfl((int)p0hi, srcA);
  int c0 = __shfl((int)p1lo, srcA), c1 = __shfl((int)p1hi, srcA);
  int b0 = __shfl((int)p0lo, srcB), b1 = __shfl((int)p0hi, srcB);
  int d0 = __shfl((int)p1lo, srcB), d1 = __shfl((int)p1hi, srcB);
  return u4_to_s8(hi ? c0 : a0, hi ? c1 : a1, hi ? d0 : b0, hi ? d1 : b1);
}

// ---------------- CSR build ----------------

__global__ void k_count(const int* __restrict__ dst1, const int* __restrict__ dst2,
                        int* __restrict__ cnt1, int* __restrict__ cnt2, int E) {
  int e = blockIdx.x * blockDim.x + threadIdx.x;
  if (e < E) {
    atomicAdd(&cnt1[dst1[e]], 1);
    atomicAdd(&cnt2[dst2[e]], 1);
  }
}

// ---- hierarchical scan (3 kernels, both count arrays batched via blockIdx.y) ----

// A: per-1024-chunk block sums
__global__ __launch_bounds__(256) void k_scanA(const int* __restrict__ cnt1, const int* __restrict__ cnt2,
                                               int* __restrict__ bs, int n) {
  int seg = blockIdx.y;
  const int* cnt = seg ? cnt2 : cnt1;
  int t = threadIdx.x;
  int idx = blockIdx.x * 1024 + t * 4;
  int sum = 0;
  if (idx + 3 < n) {
    int4 v = *(const int4*)(cnt + idx);
    sum = v.x + v.y + v.z + v.w;
  } else {
    for (int j = 0; j < 4; ++j) if (idx + j < n) sum += cnt[idx + j];
  }
  __shared__ int s[256];
  s[t] = sum;
  __syncthreads();
  for (int off = 128; off > 0; off >>= 1) {
    if (t < off) s[t] += s[t + off];
    __syncthreads();
  }
  if (t == 0) bs[seg * 64 + blockIdx.x] = s[0];
}

// B: exclusive scan of block sums (<=64 per segment), one wave per segment; writes rp[n]
__global__ __launch_bounds__(128) void k_scanB(int* __restrict__ bs, int* __restrict__ rp1,
                                               int* __restrict__ rp2, int nb, int n) {
  int w = threadIdx.x >> 6, l = threadIdx.x & 63;
  int v = (l < nb) ? bs[w * 64 + l] : 0;
  int incl = v;
  for (int off = 1; off < 64; off <<= 1) {
    int u = __shfl_up(incl, off);
    if (l >= off) incl += u;
  }
  if (l < nb) bs[w * 64 + l] = incl - v;  // exclusive block offset
  if (l == 63) {
    int* rp = w ? rp2 : rp1;
    rp[n] = incl;  // total
  }
}

// C: in-block exclusive scan + block offset -> rp and cur (fused init)
__global__ __launch_bounds__(256) void k_scanC(const int* __restrict__ cnt1, const int* __restrict__ cnt2,
                                               const int* __restrict__ bs,
                                               int* __restrict__ rp1, int* __restrict__ cur1,
                                               int* __restrict__ rp2, int* __restrict__ cur2, int n) {
  int seg = blockIdx.y;
  const int* cnt = seg ? cnt2 : cnt1;
  int* rp = seg ? rp2 : rp1;
  int* cur = seg ? cur2 : cur1;
  int t = threadIdx.x;
  int idx = blockIdx.x * 1024 + t * 4;
  int v[4] = {0, 0, 0, 0};
  if (idx + 3 < n) {
    int4 q = *(const int4*)(cnt + idx);
    v[0] = q.x; v[1] = q.y; v[2] = q.z; v[3] = q.w;
  } else {
    for (int j = 0; j < 4; ++j) if (idx + j < n) v[j] = cnt[idx + j];
  }
  int tsum = v[0] + v[1] + v[2] + v[3];
  __shared__ int s[256];
  s[t] = tsum;
  __syncthreads();
  for (int off = 1; off < 256; off <<= 1) {
    int u = (t >= off) ? s[t - off] : 0;
    __syncthreads();
    s[t] += u;
    __syncthreads();
  }
  int run = (t == 0 ? 0 : s[t - 1]) + bs[seg * 64 + blockIdx.x];
  for (int j = 0; j < 4; ++j) {
    if (idx + j < n) {
      rp[idx + j] = run;
      cur[idx + j] = run;
      run += v[j];
    }
  }
}

// fallback single-block scan (n > 65536 only)
__global__ __launch_bounds__(1024) void k_scan(const int* __restrict__ cnt, int* __restrict__ rp,
                                               int* __restrict__ cur, int n) {
  __shared__ int s[1024];
  int tid = threadIdx.x;
  int chunk = (n + 1023) >> 10;
  int beg = tid * chunk;
  int end = min(beg + chunk, n);
  int sum = 0;
  for (int i = beg; i < end; ++i) sum += cnt[i];
  s[tid] = sum;
  __syncthreads();
  for (int off = 1; off < 1024; off <<= 1) {
    int v = (tid >= off) ? s[tid - off] : 0;
    __syncthreads();
    s[tid] += v;
    __syncthreads();
  }
  int excl = (tid == 0) ? 0 : s[tid - 1];
  for (int i = beg; i < end; ++i) { rp[i] = excl; cur[i] = excl; excl += cnt[i]; }
  if (tid == 1023) rp[n] = s[1023];
}

// dst-partitioned scatter (XCD write locality); cur pre-initialized to rp
__global__ void k_scatter(const int* __restrict__ d1, const int* __restrict__ s1, const float* __restrict__ v1,
                          int* __restrict__ cur1, int2* __restrict__ c1sv,
                          const int* __restrict__ s2, const int* __restrict__ d2,
                          int* __restrict__ cur2, int* __restrict__ c2s, int E, int psize) {
  int p = blockIdx.x & 7;
  int e = (blockIdx.x >> 3) * blockDim.x + threadIdx.x;
  if (e >= E) return;
  int lo = p * psize, hi = lo + psize;
  int d = d1[e];
  if (d >= lo && d < hi) {
    int pos = atomicAdd(&cur1[d], 1);
    c1sv[pos] = make_int2(s1[e], __float_as_int(v1[e]));
  }
  int dd = d2[e];
  if (dd >= lo && dd < hi) {
    int pos = atomicAdd(&cur2[dd], 1);
    c2s[pos] = s2[e];
  }
}

// ---------------- weight prep ----------------

__global__ void k_cvtgw(const float* __restrict__ W, unsigned short* __restrict__ Wb, int total) {
  int i = (blockIdx.x * blockDim.x + threadIdx.x) * 4;
  if (i + 3 < total) {
    float4 v = *(const float4*)(W + i);
    ushort4 o;
    o.x = f2b(v.x); o.y = f2b(v.y); o.z = f2b(v.z); o.w = f2b(v.w);
    *(ushort4*)(Wb + i) = o;
  }
}

// Pack weights into MFMA fragment order: frag(t,kf) at [(t*NKF+kf)*512 + lane*8 + j]
__global__ void k_packw(const float* __restrict__ Wl, const float* __restrict__ Wr,
                        const float* __restrict__ W1, const float* __restrict__ W2,
                        unsigned short* __restrict__ Wlp, unsigned short* __restrict__ Wrp,
                        unsigned short* __restrict__ W1p, unsigned short* __restrict__ W2p) {
  int t = blockIdx.x * blockDim.x + threadIdx.x;
  if (t < 129024) {
    bool isR = t >= 64512;
    int u = isR ? t - 64512 : t;
    int i = u / 9216, v = u % 9216;
    int tt = v / 1536, r = v % 1536;
    int kf = r / 512, w = r % 512, l = w >> 3, j = w & 7;
    int c = l & 15, g = l >> 4;
    int k = kf * 32 + g * 8 + j, nn = tt * 16 + c;
    float val = (isR ? Wr : Wl)[i * 9216 + k * 96 + nn];
    (isR ? Wrp : Wlp)[u] = f2b(val);
  } else if (t < 147456) {
    int u = t - 129024;
    int tt = u / 1536, r = u % 1536;
    int kf = r / 512, w = r % 512, l = w >> 3, j = w & 7;
    int c = l & 15, g = l >> 4;
    int k = kf * 32 + g * 8 + j, nn = tt * 16 + c;
    W1p[u] = f2b(W1[k * 192 + nn]);
  } else if (t < 184320) {
    int u = t - 147456;
    int tt = u / 3072, r = u % 3072;
    int kf = r / 512, w = r % 512, l = w >> 3, j = w & 7;
    int c = l & 15, g = l >> 4;
    int k = kf * 32 + g * 8 + j, nn = tt * 16 + c;
    W2p[u] = f2b(W2[k * 192 + nn]);
  }
}

// ---------------- gc1: weighted SPMM + bias + relu + l2norm (unroll-4) ----------------

__global__ __launch_bounds__(256) void k_gc1(const int* __restrict__ rp, const int2* __restrict__ cv,
                                             const unsigned short* __restrict__ Wb,
                                             const float* __restrict__ b, unsigned short* __restrict__ out, int n) {
  int gw = (blockIdx.x * 256 + threadIdx.x) >> 6;
  int l = threadIdx.x & 63;
  if (gw >= n) return;
  int s = rp[gw], e = rp[gw + 1];
  bool act = l < 48;
  float a0 = 0.f, a1 = 0.f, b0 = 0.f, b1 = 0.f, c0 = 0.f, c1 = 0.f, d0 = 0.f, d1 = 0.f;
  int i = s;
  for (; i + 3 < e; i += 4) {
    int2 q0 = cv[i], q1 = cv[i + 1], q2 = cv[i + 2], q3 = cv[i + 3];
    if (act) {
      unsigned w0 = *(const unsigned*)(Wb + (size_t)q0.x * NH + 2 * l);
      unsigned w1 = *(const unsigned*)(Wb + (size_t)q1.x * NH + 2 * l);
      unsigned w2 = *(const unsigned*)(Wb + (size_t)q2.x * NH + 2 * l);
      unsigned w3 = *(const unsigned*)(Wb + (size_t)q3.x * NH + 2 * l);
      float v0 = __int_as_float(q0.y), v1 = __int_as_float(q1.y);
      float v2 = __int_as_float(q2.y), v3 = __int_as_float(q3.y);
      a0 = fmaf(v0, blo(w0), a0); a1 = fmaf(v0, bhi(w0), a1);
      b0 = fmaf(v1, blo(w1), b0); b1 = fmaf(v1, bhi(w1), b1);
      c0 = fmaf(v2, blo(w2), c0); c1 = fmaf(v2, bhi(w2), c1);
      d0 = fmaf(v3, blo(w3), d0); d1 = fmaf(v3, bhi(w3), d1);
    }
  }
  for (; i < e; ++i) {
    int2 q0 = cv[i];
    if (act) {
      unsigned w0 = *(const unsigned*)(Wb + (size_t)q0.x * NH + 2 * l);
      float v0 = __int_as_float(q0.y);
      a0 = fmaf(v0, blo(w0), a0); a1 = fmaf(v0, bhi(w0), a1);
    }
  }
  a0 += b0 + c0 + d0; a1 += b1 + c1 + d1;
  if (act) {
    a0 = fmaxf(a0 + b[2 * l], 0.f);
    a1 = fmaxf(a1 + b[2 * l + 1], 0.f);
  } else { a0 = a1 = 0.f; }
  float ss = a0 * a0 + a1 * a1;
#pragma unroll
  for (int o = 1; o < 64; o <<= 1) ss += __shfl_xor(ss, o);
  float sc = 1.f / fmaxf(sqrtf(ss), 1e-12f);
  if (act) {
    unsigned pk = ((unsigned)f2b(a1 * sc) << 16) | f2b(a0 * sc);
    ((unsigned*)out)[(size_t)gw * 48 + l] = pk;
  }
}

// ---------------- mean aggregation (unroll-4) — shared branch input ----------------

__global__ __launch_bounds__(256) void k_agg(const int* __restrict__ rp, const int* __restrict__ csrc,
                                             const unsigned short* __restrict__ X,
                                             unsigned short* __restrict__ out, int n) {
  int gw = (blockIdx.x * 256 + threadIdx.x) >> 6;
  int l = threadIdx.x & 63;
  if (gw >= n) return;
  int s = rp[gw], e = rp[gw + 1];
  bool act = l < 48;
  float a0 = 0.f, a1 = 0.f, b0 = 0.f, b1 = 0.f, c0 = 0.f, c1 = 0.f, d0 = 0.f, d1 = 0.f;
  int i = s;
  for (; i + 3 < e; i += 4) {
    int s0 = csrc[i], s1 = csrc[i + 1], s2 = csrc[i + 2], s3 = csrc[i + 3];
    if (act) {
      unsigned w0 = *(const unsigned*)(X + (size_t)s0 * NH + 2 * l);
      unsigned w1 = *(const unsigned*)(X + (size_t)s1 * NH + 2 * l);
      unsigned w2 = *(const unsigned*)(X + (size_t)s2 * NH + 2 * l);
      unsigned w3 = *(const unsigned*)(X + (size_t)s3 * NH + 2 * l);
      a0 += blo(w0); a1 += bhi(w0);
      b0 += blo(w1); b1 += bhi(w1);
      c0 += blo(w2); c1 += bhi(w2);
      d0 += blo(w3); d1 += bhi(w3);
    }
  }
  for (; i < e; ++i) {
    int s0 = csrc[i];
    if (act) {
      unsigned w0 = *(const unsigned*)(X + (size_t)s0 * NH + 2 * l);
      a0 += blo(w0); a1 += bhi(w0);
    }
  }
  a0 += b0 + c0 + d0; a1 += b1 + c1 + d1;
  float inv = 1.f / fmaxf((float)(e - s), 1.f);
  if (act) {
    unsigned pk = ((unsigned)f2b(a1 * inv) << 16) | f2b(a0 * inv);
    ((unsigned*)out)[(size_t)gw * 48 + l] = pk;
  }
}

// ---------------- trunk fused agg+SAGE, T=1, LDS-staged weights ----------------

template <int EPI>
__global__ __launch_bounds__(256) void k_sageagg(const int* __restrict__ rp, const int* __restrict__ csrc,
                                                 const unsigned short* __restrict__ X,
                                                 const unsigned short* __restrict__ Wlp,
                                                 const unsigned short* __restrict__ Wrp,
                                                 const float* __restrict__ bias,
                                                 unsigned short* __restrict__ Y, int n) {
  __shared__ __align__(16) unsigned short sw[18432];
  int tid = threadIdx.x;
  int l = tid & 63;
  int m0 = (blockIdx.x * 4 + (tid >> 6)) * 16;
  int c = l & 15, g = l >> 4;

  stage(sw, Wlp, 9216, tid);
  stage(sw + 9216, Wrp, 9216, tid);
  __syncthreads();

  int nd = min(m0 + c, n - 1);
  int s = rp[nd], e = rp[nd + 1];

  float aa[3][8], bb[3][8];
#pragma unroll
  for (int kf = 0; kf < 3; ++kf)
#pragma unroll
    for (int j = 0; j < 8; ++j) { aa[kf][j] = 0.f; bb[kf][j] = 0.f; }

  const unsigned short* Xg = X + g * 8;
  int i = s;
  for (; i + 1 < e; i += 2) {
    const unsigned short* xr0 = Xg + (size_t)csrc[i] * NH;
    const unsigned short* xr1 = Xg + (size_t)csrc[i + 1] * NH;
    short8 a0 = *(const short8*)(xr0);
    short8 a1 = *(const short8*)(xr0 + 32);
    short8 a2 = *(const short8*)(xr0 + 64);
    short8 b0 = *(const short8*)(xr1);
    short8 b1 = *(const short8*)(xr1 + 32);
    short8 b2 = *(const short8*)(xr1 + 64);
#pragma unroll
    for (int j = 0; j < 8; ++j) {
      aa[0][j] += b2f(a0[j]); aa[1][j] += b2f(a1[j]); aa[2][j] += b2f(a2[j]);
      bb[0][j] += b2f(b0[j]); bb[1][j] += b2f(b1[j]); bb[2][j] += b2f(b2[j]);
    }
  }
  if (i < e) {
    const unsigned short* xr0 = Xg + (size_t)csrc[i] * NH;
    short8 a0 = *(const short8*)(xr0);
    short8 a1 = *(const short8*)(xr0 + 32);
    short8 a2 = *(const short8*)(xr0 + 64);
#pragma unroll
    for (int j = 0; j < 8; ++j) {
      aa[0][j] += b2f(a0[j]); aa[1][j] += b2f(a1[j]); aa[2][j] += b2f(a2[j]);
    }
  }
  float inv = 1.f / fmaxf((float)(e - s), 1.f);
  short8 af[3];
#pragma unroll
  for (int kf = 0; kf < 3; ++kf)
#pragma unroll
    for (int j = 0; j < 8; ++j) af[kf][j] = (short)f2b((aa[kf][j] + bb[kf][j]) * inv);

  size_t aoff = (size_t)nd * NH + g * 8;
  short8 xf[3];
#pragma unroll
  for (int kf = 0; kf < 3; ++kf) xf[kf] = *(const short8*)(X + aoff + kf * 32);

  f32x4 acc[6];
#pragma unroll
  for (int t = 0; t < 6; ++t) acc[t] = (f32x4){0.f, 0.f, 0.f, 0.f};
#pragma unroll
  for (int kf = 0; kf < 3; ++kf) {
#pragma unroll
    for (int t = 0; t < 6; ++t) {
      short8 wlf = WFRAG(sw, t * 3 + kf);
      acc[t] = MFMA(wlf, af[kf], acc[t]);
    }
#pragma unroll
    for (int t = 0; t < 6; ++t) {
      short8 wrf = WFRAG(sw + 9216, t * 3 + kf);
      acc[t] = MFMA(wrf, xf[kf], acc[t]);
    }
  }

  float v[6][4];
  float ss = 0.f;
#pragma unroll
  for (int t = 0; t < 6; ++t) {
    float4 bv = *(const float4*)(bias + t * 16 + g * 4);
#pragma unroll
    for (int r = 0; r < 4; ++r) {
      float x = fmaxf(acc[t][r] + ((const float*)&bv)[r], 0.f);
      v[t][r] = x;
      ss = fmaf(x, x, ss);
    }
  }
  if (EPI == 0) {
    ss += __shfl_xor(ss, 16);
    ss += __shfl_xor(ss, 32);
    float sc = 1.f / fmaxf(sqrtf(ss), 1e-12f);
#pragma unroll
    for (int t = 0; t < 6; ++t)
#pragma unroll
      for (int r = 0; r < 4; ++r) v[t][r] *= sc;
  }
  if (m0 + c < n) {
    unsigned short* yr = Y + (size_t)(m0 + c) * NH;
#pragma unroll
    for (int t = 0; t < 6; ++t)
      *(uint2*)(yr + t * 16 + g * 4) = make_uint2(cvt_pk(v[t][0], v[t][1]), cvt_pk(v[t][2], v[t][3]));
  }
}

// ---------------- fused 3-layer MLP, T=2, LDS-staged weights: score += mlp(X) ----------------

__global__ __launch_bounds__(256) void k_mlp(const unsigned short* __restrict__ X,
                                             const unsigned short* __restrict__ W1p, const float* __restrict__ b1,
                                             const unsigned short* __restrict__ W2p, const float* __restrict__ b2,
                                             const float* __restrict__ W3, const float* __restrict__ b3,
                                             float* __restrict__ score, int n) {
  __shared__ __align__(16) unsigned short sw[18432];
  int tid = threadIdx.x;
  int l = tid & 63;
  int m0 = (blockIdx.x * 4 + (tid >> 6)) * 32;
  int c = l & 15, g = l >> 4;
  int srcA = c + ((g & 1) << 5), srcB = srcA + 16, hi = g >> 1;
  int rA = min(m0 + c, n - 1), rB = min(m0 + 16 + c, n - 1);

  stage(sw, W1p, 18432, tid);

  short8 xf[2][3];
#pragma unroll
  for (int kf = 0; kf < 3; ++kf) {
    xf[0][kf] = *(const short8*)(X + (size_t)rA * NH + kf * 32 + g * 8);
    xf[1][kf] = *(const short8*)(X + (size_t)rB * NH + kf * 32 + g * 8);
  }
  __syncthreads();

  // MLP1, t-outer
  unsigned pk1[2][12][2];
#pragma unroll
  for (int t = 0; t < 12; ++t) {
    f32x4 a0 = (f32x4){0.f, 0.f, 0.f, 0.f};
    f32x4 a1 = (f32x4){0.f, 0.f, 0.f, 0.f};
#pragma unroll
    for (int kf = 0; kf < 3; ++kf) {
      short8 wf = WFRAG(sw, t * 3 + kf);
      a0 = MFMA(wf, xf[0][kf], a0);
      a1 = MFMA(wf, xf[1][kf], a1);
    }
    float4 bv = *(const float4*)(b1 + t * 16 + g * 4);
    pk1[0][t][0] = cvt_pk(fmaxf(a0[0] + bv.x, 0.f), fmaxf(a0[1] + bv.y, 0.f));
    pk1[0][t][1] = cvt_pk(fmaxf(a0[2] + bv.z, 0.f), fmaxf(a0[3] + bv.w, 0.f));
    pk1[1][t][0] = cvt_pk(fmaxf(a1[0] + bv.x, 0.f), fmaxf(a1[1] + bv.y, 0.f));
    pk1[1][t][1] = cvt_pk(fmaxf(a1[2] + bv.z, 0.f), fmaxf(a1[3] + bv.w, 0.f));
  }

  short8 af2[2][6];
#pragma unroll
  for (int kf = 0; kf < 6; ++kf) {
    af2[0][kf] = xchg(pk1[0][2 * kf][0], pk1[0][2 * kf][1], pk1[0][2 * kf + 1][0], pk1[0][2 * kf + 1][1], srcA, srcB, hi);
    af2[1][kf] = xchg(pk1[1][2 * kf][0], pk1[1][2 * kf][1], pk1[1][2 * kf + 1][0], pk1[1][2 * kf + 1][1], srcA, srcB, hi);
  }

  float sv0 = 0.f, sv1 = 0.f;
#pragma unroll
  for (int h = 0; h < 2; ++h) {
    __syncthreads();
    stage(sw, W2p + h * 18432, 18432, tid);
    __syncthreads();
#pragma unroll
    for (int tt = 0; tt < 6; ++tt) {
      int t = h * 6 + tt;
      f32x4 a0 = (f32x4){0.f, 0.f, 0.f, 0.f};
      f32x4 a1 = (f32x4){0.f, 0.f, 0.f, 0.f};
#pragma unroll
      for (int kf = 0; kf < 6; ++kf) {
        short8 wf = WFRAG(sw, tt * 6 + kf);
        a0 = MFMA(wf, af2[0][kf], a0);
        a1 = MFMA(wf, af2[1][kf], a1);
      }
      float4 bv = *(const float4*)(b2 + t * 16 + g * 4);
      float4 wv3 = *(const float4*)(W3 + t * 16 + g * 4);
#pragma unroll
      for (int r = 0; r < 4; ++r) {
        sv0 = fmaf(fmaxf(a0[r] + ((const float*)&bv)[r], 0.f), ((const float*)&wv3)[r], sv0);
        sv1 = fmaf(fmaxf(a1[r] + ((const float*)&bv)[r], 0.f), ((const float*)&wv3)[r], sv1);
      }
    }
  }
  sv0 += __shfl_xor(sv0, 16); sv0 += __shfl_xor(sv0, 32);
  sv1 += __shfl_xor(sv1, 16); sv1 += __shfl_xor(sv1, 32);
  if (g == 0) {
    float b3v = b3[0];
    if (m0 + c < n) score[m0 + c] += sv0 + b3v;
    if (m0 + 16 + c < n) score[m0 + 16 + c] += sv1 + b3v;
  }
}

// ---------------- per-branch, T=2, LDS-staged weights ----------------

__global__ __launch_bounds__(256) void k_branch(const unsigned short* __restrict__ Ag,
                                                const unsigned short* __restrict__ X21,
                                                const unsigned short* __restrict__ Wlp,
                                                const unsigned short* __restrict__ Wrp,
                                                const float* __restrict__ sbl,
                                                const unsigned short* __restrict__ W1p, const float* __restrict__ b1,
                                                const unsigned short* __restrict__ W2p, const float* __restrict__ b2,
                                                const float* __restrict__ W3, const float* __restrict__ b3,
                                                unsigned short* __restrict__ Xb, float* __restrict__ score,
                                                int n, int gblk) {
  __shared__ __align__(16) unsigned short sw[18432];
  int bb = blockIdx.x / gblk;
  int blk = blockIdx.x - bb * gblk;
  int tid = threadIdx.x;
  int l = tid & 63;
  int m0 = (blk * 4 + (tid >> 6)) * 32;
  int c = l & 15, g = l >> 4;
  int srcA = c + ((g & 1) << 5), srcB = srcA + 16, hi = g >> 1;
  int rA = min(m0 + c, n - 1), rB = min(m0 + 16 + c, n - 1);
  size_t aoffA = (size_t)rA * NH + g * 8, aoffB = (size_t)rB * NH + g * 8;

  const float* bl = sbl + (size_t)bb * NH;

  stage(sw, Wlp + (size_t)bb * 9216, 9216, tid);
  stage(sw + 9216, Wrp + (size_t)bb * 9216, 9216, tid);

  short8 agf[2][3], xf[2][3];
#pragma unroll
  for (int kf = 0; kf < 3; ++kf) {
    agf[0][kf] = *(const short8*)(Ag + aoffA + kf * 32);
    agf[1][kf] = *(const short8*)(Ag + aoffB + kf * 32);
    xf[0][kf] = *(const short8*)(X21 + aoffA + kf * 32);
    xf[1][kf] = *(const short8*)(X21 + aoffB + kf * 32);
  }
  __syncthreads();

  // ---- SAGE, t-outer ----
  float v[2][6][4];
  float ss0 = 0.f, ss1 = 0.f;
#pragma unroll
  for (int t = 0; t < 6; ++t) {
    f32x4 a0 = (f32x4){0.f, 0.f, 0.f, 0.f};
    f32x4 a1 = (f32x4){0.f, 0.f, 0.f, 0.f};
#pragma unroll
    for (int kf = 0; kf < 3; ++kf) {
      short8 wlf = WFRAG(sw, t * 3 + kf);
      a0 = MFMA(wlf, agf[0][kf], a0);
      a1 = MFMA(wlf, agf[1][kf], a1);
      short8 wrf = WFRAG(sw + 9216, t * 3 + kf);
      a0 = MFMA(wrf, xf[0][kf], a0);
      a1 = MFMA(wrf, xf[1][kf], a1);
    }
    float4 bv = *(const float4*)(bl + t * 16 + g * 4);
#pragma unroll
    for (int r = 0; r < 4; ++r) {
      float x0 = fmaxf(a0[r] + ((const float*)&bv)[r], 0.f);
      float x1 = fmaxf(a1[r] + ((const float*)&bv)[r], 0.f);
      v[0][t][r] = x0; ss0 = fmaf(x0, x0, ss0);
      v[1][t][r] = x1; ss1 = fmaf(x1, x1, ss1);
    }
  }
  ss0 += __shfl_xor(ss0, 16); ss0 += __shfl_xor(ss0, 32);
  ss1 += __shfl_xor(ss1, 16); ss1 += __shfl_xor(ss1, 32);
  float sc0 = 1.f / fmaxf(sqrtf(ss0), 1e-12f);
  float sc1 = 1.f / fmaxf(sqrtf(ss1), 1e-12f);

  unsigned pk[2][6][2];
#pragma unroll
  for (int t = 0; t < 6; ++t) {
    pk[0][t][0] = cvt_pk(v[0][t][0] * sc0, v[0][t][1] * sc0);
    pk[0][t][1] = cvt_pk(v[0][t][2] * sc0, v[0][t][3] * sc0);
    pk[1][t][0] = cvt_pk(v[1][t][0] * sc1, v[1][t][1] * sc1);
    pk[1][t][1] = cvt_pk(v[1][t][2] * sc1, v[1][t][3] * sc1);
  }
  if (bb == 0) {
    if (m0 + c < n) {
      unsigned short* yr = Xb + (size_t)(m0 + c) * NH;
#pragma unroll
      for (int t = 0; t < 6; ++t) *(uint2*)(yr + t * 16 + g * 4) = make_uint2(pk[0][t][0], pk[0][t][1]);
    }
    if (m0 + 16 + c < n) {
      unsigned short* yr = Xb + (size_t)(m0 + 16 + c) * NH;
#pragma unroll
      for (int t = 0; t < 6; ++t) *(uint2*)(yr + t * 16 + g * 4) = make_uint2(pk[1][t][0], pk[1][t][1]);
    }
  }

  // ---- MLP1, t-outer ----
  __syncthreads();
  stage(sw, W1p, 18432, tid);
  short8 af1[2][3];
#pragma unroll
  for (int kf = 0; kf < 3; ++kf) {
    af1[0][kf] = xchg(pk[0][2 * kf][0], pk[0][2 * kf][1], pk[0][2 * kf + 1][0], pk[0][2 * kf + 1][1], srcA, srcB, hi);
    af1[1][kf] = xchg(pk[1][2 * kf][0], pk[1][2 * kf][1], pk[1][2 * kf + 1][0], pk[1][2 * kf + 1][1], srcA, srcB, hi);
  }
  __syncthreads();
  unsigned pk1[2][12][2];
#pragma unroll
  for (int t = 0; t < 12; ++t) {
    f32x4 a0 = (f32x4){0.f, 0.f, 0.f, 0.f};
    f32x4 a1 = (f32x4){0.f, 0.f, 0.f, 0.f};
#pragma unroll
    for (int kf = 0; kf < 3; ++kf) {
      short8 wf = WFRAG(sw, t * 3 + kf);
      a0 = MFMA(wf, af1[0][kf], a0);
      a1 = MFMA(wf, af1[1][kf], a1);
    }
    float4 bv = *(const float4*)(b1 + t * 16 + g * 4);
    pk1[0][t][0] = cvt_pk(fmaxf(a0[0] + bv.x, 0.f), fmaxf(a0[1] + bv.y, 0.f));
    pk1[0][t][1] = cvt_pk(fmaxf(a0[2] + bv.z, 0.f), fmaxf(a0[3] + bv.w, 0.f));
    pk1[1][t][0] = cvt_pk(fmaxf(a1[0] + bv.x, 0.f), fmaxf(a1[1] + bv.y, 0.f));
    pk1[1][t][1] = cvt_pk(fmaxf(a1[2] + bv.z, 0.f), fmaxf(a1[3] + bv.w, 0.f));
  }

  // ---- MLP2+3, t-outer, W2 staged in two halves ----
  short8 af2[2][6];
#pragma unroll
  for (int kf = 0; kf < 6; ++kf) {
    af2[0][kf] = xchg(pk1[0][2 * kf][0], pk1[0][2 * kf][1], pk1[0][2 * kf + 1][0], pk1[0][2 * kf + 1][1], srcA, srcB, hi);
    af2[1][kf] = xchg(pk1[1][2 * kf][0], pk1[1][2 * kf][1], pk1[1][2 * kf + 1][0], pk1[1][2 * kf + 1][1], srcA, srcB, hi);
  }
  float sv0 = 0.f, sv1 = 0.f;
#pragma unroll
  for (int h = 0; h < 2; ++h) {
    __syncthreads();
    stage(sw, W2p + h * 18432, 18432, tid);
    __syncthreads();
#pragma unroll
    for (int tt = 0; tt < 6; ++tt) {
      int t = h * 6 + tt;
      f32x4 a0 = (f32x4){0.f, 0.f, 0.f, 0.f};
      f32x4 a1 = (f32x4){0.f, 0.f, 0.f, 0.f};
#pragma unroll
      for (int kf = 0; kf < 6; ++kf) {
        short8 wf = WFRAG(sw, tt * 6 + kf);
        a0 = MFMA(wf, af2[0][kf], a0);
        a1 = MFMA(wf, af2[1][kf], a1);
      }
      float4 bv = *(const float4*)(b2 + t * 16 + g * 4);
      float4 wv3 = *(const float4*)(W3 + t * 16 + g * 4);
#pragma unroll
      for (int r = 0; r < 4; ++r) {
        sv0 = fmaf(fmaxf(a0[r] + ((const float*)&bv)[r], 0.f), ((const float*)&wv3)[r], sv0);
        sv1 = fmaf(fmaxf(a1[r] + ((const float*)&bv)[r], 0.f), ((const float*)&wv3)[r], sv1);
      }
    }
  }
  sv0 += __shfl_xor(sv0, 16); sv0 += __shfl_xor(sv0, 32);
  sv1 += __shfl_xor(sv1, 16); sv1 += __shfl_xor(sv1, 32);
  if (g == 0) {
    float b3v = b3[0];
    if (m0 + c < n) atomicAdd(&score[m0 + c], sv0 + b3v);
    if (m0 + 16 + c < n) atomicAdd(&score[m0 + 16 + c], sv1 + b3v);
  }
}

// ---------------- host ----------------

extern "C" void kernel_launch(void* const* d_in, const int* in_sizes, int n_in,
                              void* d_out, int out_size, void* d_ws, size_t ws_size,
                              hipStream_t stream) {
  const int* ei1 = (const int*)d_in[0];
  const float* ev1 = (const float*)d_in[1];
  const int* ei2 = (const int*)d_in[2];
  const float* gW = (const float*)d_in[3];
  const float* gb = (const float*)d_in[4];
  const float* sWl = (const float*)d_in[5];
  const float* sbl = (const float*)d_in[6];
  const float* sWr = (const float*)d_in[7];
  const float* W1 = (const float*)d_in[8];
  const float* b1 = (const float*)d_in[9];
  const float* W2 = (const float*)d_in[10];
  const float* b2 = (const float*)d_in[11];
  const float* W3 = (const float*)d_in[12];
  const float* b3 = (const float*)d_in[13];
  float* score = (float*)d_out;

  const int E = in_sizes[0] / 2;
  const int n = in_sizes[3] / NH;

  const int* d1 = ei1;      // edge_index1[0] = dst
  const int* s1 = ei1 + E;  // edge_index1[1] = src
  const int* s2 = ei2;      // edge_index2[0] = src
  const int* d2 = ei2 + E;  // edge_index2[1] = dst

  char* w = (char*)d_ws;
  auto alloc = [&](size_t bytes) {
    char* p = w;
    w += (bytes + 255) & ~(size_t)255;
    return p;
  };
  int* cnt1 = (int*)alloc((size_t)n * 4);
  int* cnt2 = (int*)alloc((size_t)n * 4);
  int* cur1 = (int*)alloc((size_t)n * 4);
  int* cur2 = (int*)alloc((size_t)n * 4);
  int* rp1 = (int*)alloc((size_t)(n + 1) * 4);
  int* rp2 = (int*)alloc((size_t)(n + 1) * 4);
  int* bs = (int*)alloc(128 * 4);
  int2* c1sv = (int2*)alloc((size_t)E * 8);
  int* c2s = (int*)alloc((size_t)E * 4);
  unsigned short* gwb = (unsigned short*)alloc((size_t)n * NH * 2);
  unsigned short* wlp = (unsigned short*)alloc((size_t)7 * NH * NH * 2);
  unsigned short* wrp = (unsigned short*)alloc((size_t)7 * NH * NH * 2);
  unsigned short* w1p = (unsigned short*)alloc((size_t)NH * NH2 * 2);
  unsigned short* w2p = (unsigned short*)alloc((size_t)NH2 * NH2 * 2);
  unsigned short* x21 = (unsigned short*)alloc((size_t)n * NH * 2);
  unsigned short* Ag = (unsigned short*)alloc((size_t)n * NH * 2);
  unsigned short* xb = (unsigned short*)alloc((size_t)n * NH * 2);
  unsigned short* tb = (unsigned short*)alloc((size_t)n * NH * 2);

  // zero cnt1+cnt2 (contiguous region) + score
  size_t zbytes = (size_t)((char*)cur1 - (char*)cnt1) + (size_t)n * 4;
  hipMemsetAsync(cnt1, 0, zbytes, stream);
  hipMemsetAsync(score, 0, (size_t)n * 4, stream);

  int eb = (E + 255) / 256;
  int nb4 = (n + 3) / 4;          // wave-per-node kernels
  int sblk = (n + 63) / 64;       // T=1 staged agg+sage: 4 waves x 16 nodes
  int gblk = (n + 127) / 128;     // T=2 MFMA kernels: 4 waves x 32 nodes
  int psize = (n + 7) / 8;        // dst-partition size for scatter
  int nb1024 = (n + 1023) / 1024; // hierarchical scan blocks per segment

  k_count<<<eb, 256, 0, stream>>>(d1, d2, cnt1, cnt2, E);
  if (nb1024 <= 64) {
    k_scanA<<<dim3(nb1024, 2), 256, 0, stream>>>(cnt1, cnt2, bs, n);
    k_scanB<<<1, 128, 0, stream>>>(bs, rp1, rp2, nb1024, n);
    k_scanC<<<dim3(nb1024, 2), 256, 0, stream>>>(cnt1, cnt2, bs, rp1, cur1, rp2, cur2, n);
  } else {
    k_scan<<<1, 1024, 0, stream>>>(cnt1, rp1, cur1, n);
    k_scan<<<1, 1024, 0, stream>>>(cnt2, rp2, cur2, n);
  }
  k_scatter<<<eb * 8, 256, 0, stream>>>(d1, s1, ev1, cur1, c1sv, s2, d2, cur2, c2s, E, psize);

  k_cvtgw<<<(n * NH / 4 + 255) / 256, 256, 0, stream>>>(gW, gwb, n * NH);
  k_packw<<<720, 256, 0, stream>>>(sWl, sWr, W1, W2, wlp, wrp, w1p, w2p);

  // x2_1 = l2norm(relu(spmm(adj1, gc1_W) + gc1_b))
  k_gc1<<<nb4, 256, 0, stream>>>(rp1, c1sv, gwb, gb, x21, n);

  // score += mlp(x2_1)
  k_mlp<<<gblk, 256, 0, stream>>>(x21, w1p, b1, w2p, b2, W3, b3, score, n);

  // Ag = mean-agg(x2_1) — shared by all 6 score branches (incl. trunk layer 0)
  k_agg<<<nb4, 256, 0, stream>>>(rp2, c2s, x21, Ag, n);

  // 6 score branches (branch 0 emits xb = trunk layer-0 out)
  k_branch<<<6 * gblk, 256, 0, stream>>>(Ag, x21, wlp, wrp, sbl, w1p, b1, w2p, b2, W3, b3,
                                         xb, score, n, gblk);

  // trunk layers 1..5 (fused agg+sage, T=1 staged)
  unsigned short* xc = xb;
  unsigned short* xn = tb;
  for (int i = 1; i < 6; ++i) {
    k_sageagg<0><<<sblk, 256, 0, stream>>>(rp2, c2s, xc, wlp + (size_t)i * 9216,
                                           wrp + (size_t)i * 9216, sbl + (size_t)i * NH, xn, n);
    unsigned short* tmp = xc; xc = xn; xn = tmp;
  }

  // last layer: relu only, then final mlp
  k_sageagg<1><<<sblk, 256, 0, stream>>>(rp2, c2s, xc, wlp + (size_t)6 * 9216,
                                         wrp + (size_t)6 * 9216, sbl + (size_t)6 * NH, xn, n);
  k_mlp<<<gblk, 256, 0, stream>>>(xn, w1p, b1, w2p, b2, W3, b3, score, n);

  (void)n_in; (void)out_size; (void)ws_size;
}

// Round 13
// 553.360 us; speedup vs baseline: 1.3821x; 1.0116x over previous
//
#include <hip/hip_runtime.h>

#define NH 96
#define NH2 192

typedef __attribute__((ext_vector_type(8))) short short8;
typedef __attribute__((ext_vector_type(4))) float f32x4;

__device__ __forceinline__ unsigned short f2b(float f) {
  unsigned u = __float_as_uint(f);
  unsigned r = (u + 0x7FFFu + ((u >> 16) & 1u)) >> 16;
  return (unsigned short)r;
}
__device__ __forceinline__ float blo(unsigned w) { return __uint_as_float(w << 16); }
__device__ __forceinline__ float bhi(unsigned w) { return __uint_as_float(w & 0xFFFF0000u); }
__device__ __forceinline__ float b2f(short v) { return __uint_as_float(((unsigned)(unsigned short)v) << 16); }

__device__ __forceinline__ unsigned cvt_pk(float lo, float hi) {
  unsigned r;
  asm("v_cvt_pk_bf16_f32 %0, %1, %2" : "=v"(r) : "v"(lo), "v"(hi));
  return r;
}

__device__ __forceinline__ short8 u4_to_s8(int a, int b, int c, int d) {
  union { int u[4]; short8 s; } x;
  x.u[0] = a; x.u[1] = b; x.u[2] = c; x.u[3] = d;
  return x.s;
}

#define MFMA(a, b, c) __builtin_amdgcn_mfma_f32_16x16x32_bf16((a), (b), (c), 0, 0, 0)
#define WFRAG(p, idx) (*(const short8*)((p) + ((idx) << 9) + (l << 3)))

// block-cooperative weight staging: global -> LDS, 16B per thread per iter
__device__ __forceinline__ void stage(unsigned short* dst, const unsigned short* src, int nshorts,
                                      int tid, int nt) {
  const uint4* s = (const uint4*)src;
  uint4* d = (uint4*)dst;
  int nv = nshorts >> 3;
  for (int i = tid; i < nv; i += nt) d[i] = s[i];
}

// cross-g exchange: target lane (c,g) builds B-fragment elems H[c][kf*32+g*8+j]
__device__ __forceinline__ short8 xchg(unsigned p0lo, unsigned p0hi, unsigned p1lo, unsigned p1hi,
                                       int srcA, int srcB, int hi) {
  int a0 = __shfl((int)p0lo, srcA), a1 = __shfl((int)p0hi, srcA);
  int c0 = __shfl((int)p1lo, srcA), c1 = __shfl((int)p1hi, srcA);
  int b0 = __shfl((int)p0lo, srcB), b1 = __shfl((int)p0hi, srcB);
  int d0 = __shfl((int)p1lo, srcB), d1 = __shfl((int)p1hi, srcB);
  return u4_to_s8(hi ? c0 : a0, hi ? c1 : a1, hi ? d0 : b0, hi ? d1 : b1);
}

// ---------------- CSR build ----------------

// dst-partitioned count (XCD locality on the atomics)
__global__ void k_count(const int* __restrict__ dst1, const int* __restrict__ dst2,
                        int* __restrict__ cnt1, int* __restrict__ cnt2, int E, int psize) {
  int p = blockIdx.x & 7;
  int e = (blockIdx.x >> 3) * blockDim.x + threadIdx.x;
  if (e >= E) return;
  int lo = p * psize, hi = lo + psize;
  int d = dst1[e];
  if (d >= lo && d < hi) atomicAdd(&cnt1[d], 1);
  int dd = dst2[e];
  if (dd >= lo && dd < hi) atomicAdd(&cnt2[dd], 1);
}

// ---- hierarchical scan (3 kernels, both count arrays batched via blockIdx.y) ----

__global__ __launch_bounds__(256) void k_scanA(const int* __restrict__ cnt1, const int* __restrict__ cnt2,
                                               int* __restrict__ bs, int n) {
  int seg = blockIdx.y;
  const int* cnt = seg ? cnt2 : cnt1;
  int t = threadIdx.x;
  int idx = blockIdx.x * 1024 + t * 4;
  int sum = 0;
  if (idx + 3 < n) {
    int4 v = *(const int4*)(cnt + idx);
    sum = v.x + v.y + v.z + v.w;
  } else {
    for (int j = 0; j < 4; ++j) if (idx + j < n) sum += cnt[idx + j];
  }
  __shared__ int s[256];
  s[t] = sum;
  __syncthreads();
  for (int off = 128; off > 0; off >>= 1) {
    if (t < off) s[t] += s[t + off];
    __syncthreads();
  }
  if (t == 0) bs[seg * 64 + blockIdx.x] = s[0];
}

__global__ __launch_bounds__(128) void k_scanB(int* __restrict__ bs, int* __restrict__ rp1,
                                               int* __restrict__ rp2, int nb, int n) {
  int w = threadIdx.x >> 6, l = threadIdx.x & 63;
  int v = (l < nb) ? bs[w * 64 + l] : 0;
  int incl = v;
  for (int off = 1; off < 64; off <<= 1) {
    int u = __shfl_up(incl, off);
    if (l >= off) incl += u;
  }
  if (l < nb) bs[w * 64 + l] = incl - v;
  if (l == 63) {
    int* rp = w ? rp2 : rp1;
    rp[n] = incl;
  }
}

__global__ __launch_bounds__(256) void k_scanC(const int* __restrict__ cnt1, const int* __restrict__ cnt2,
                                               const int* __restrict__ bs,
                                               int* __restrict__ rp1, int* __restrict__ cur1,
                                               int* __restrict__ rp2, int* __restrict__ cur2, int n) {
  int seg = blockIdx.y;
  const int* cnt = seg ? cnt2 : cnt1;
  int* rp = seg ? rp2 : rp1;
  int* cur = seg ? cur2 : cur1;
  int t = threadIdx.x;
  int idx = blockIdx.x * 1024 + t * 4;
  int v[4] = {0, 0, 0, 0};
  if (idx + 3 < n) {
    int4 q = *(const int4*)(cnt + idx);
    v[0] = q.x; v[1] = q.y; v[2] = q.z; v[3] = q.w;
  } else {
    for (int j = 0; j < 4; ++j) if (idx + j < n) v[j] = cnt[idx + j];
  }
  int tsum = v[0] + v[1] + v[2] + v[3];
  __shared__ int s[256];
  s[t] = tsum;
  __syncthreads();
  for (int off = 1; off < 256; off <<= 1) {
    int u = (t >= off) ? s[t - off] : 0;
    __syncthreads();
    s[t] += u;
    __syncthreads();
  }
  int run = (t == 0 ? 0 : s[t - 1]) + bs[seg * 64 + blockIdx.x];
  for (int j = 0; j < 4; ++j) {
    if (idx + j < n) {
      rp[idx + j] = run;
      cur[idx + j] = run;
      run += v[j];
    }
  }
}

// fallback single-block scan (n > 65536 only)
__global__ __launch_bounds__(1024) void k_scan(const int* __restrict__ cnt, int* __restrict__ rp,
                                               int* __restrict__ cur, int n) {
  __shared__ int s[1024];
  int tid = threadIdx.x;
  int chunk = (n + 1023) >> 10;
  int beg = tid * chunk;
  int end = min(beg + chunk, n);
  int sum = 0;
  for (int i = beg; i < end; ++i) sum += cnt[i];
  s[tid] = sum;
  __syncthreads();
  for (int off = 1; off < 1024; off <<= 1) {
    int v = (tid >= off) ? s[tid - off] : 0;
    __syncthreads();
    s[tid] += v;
    __syncthreads();
  }
  int excl = (tid == 0) ? 0 : s[tid - 1];
  for (int i = beg; i < end; ++i) { rp[i] = excl; cur[i] = excl; excl += cnt[i]; }
  if (tid == 1023) rp[n] = s[1023];
}

// dst-partitioned scatter (XCD write locality); cur pre-initialized to rp
__global__ void k_scatter(const int* __restrict__ d1, const int* __restrict__ s1, const float* __restrict__ v1,
                          int* __restrict__ cur1, int2* __restrict__ c1sv,
                          const int* __restrict__ s2, const int* __restrict__ d2,
                          int* __restrict__ cur2, int* __restrict__ c2s, int E, int psize) {
  int p = blockIdx.x & 7;
  int e = (blockIdx.x >> 3) * blockDim.x + threadIdx.x;
  if (e >= E) return;
  int lo = p * psize, hi = lo + psize;
  int d = d1[e];
  if (d >= lo && d < hi) {
    int pos = atomicAdd(&cur1[d], 1);
    c1sv[pos] = make_int2(s1[e], __float_as_int(v1[e]));
  }
  int dd = d2[e];
  if (dd >= lo && dd < hi) {
    int pos = atomicAdd(&cur2[dd], 1);
    c2s[pos] = s2[e];
  }
}

// ---------------- weight prep: pack W's into fragment order AND convert gW -> bf16 ----------------
// frag(t,kf) at [(t*NKF+kf)*512 + lane*8 + j], value = W[k][nn], k=kf*32+(lane>>4)*8+j, nn=t*16+(lane&15)

__global__ void k_prep(const float* __restrict__ Wl, const float* __restrict__ Wr,
                       const float* __restrict__ W1, const float* __restrict__ W2,
                       const float* __restrict__ gW,
                       unsigned short* __restrict__ Wlp, unsigned short* __restrict__ Wrp,
                       unsigned short* __restrict__ W1p, unsigned short* __restrict__ W2p,
                       unsigned short* __restrict__ gwb, int gtotal) {
  int t = blockIdx.x * blockDim.x + threadIdx.x;
  if (t < 129024) {
    bool isR = t >= 64512;
    int u = isR ? t - 64512 : t;
    int i = u / 9216, v = u % 9216;
    int tt = v / 1536, r = v % 1536;
    int kf = r / 512, w = r % 512, l = w >> 3, j = w & 7;
    int c = l & 15, g = l >> 4;
    int k = kf * 32 + g * 8 + j, nn = tt * 16 + c;
    float val = (isR ? Wr : Wl)[i * 9216 + k * 96 + nn];
    (isR ? Wrp : Wlp)[u] = f2b(val);
  } else if (t < 147456) {
    int u = t - 129024;
    int tt = u / 1536, r = u % 1536;
    int kf = r / 512, w = r % 512, l = w >> 3, j = w & 7;
    int c = l & 15, g = l >> 4;
    int k = kf * 32 + g * 8 + j, nn = tt * 16 + c;
    W1p[u] = f2b(W1[k * 192 + nn]);
  } else if (t < 184320) {
    int u = t - 147456;
    int tt = u / 3072, r = u % 3072;
    int kf = r / 512, w = r % 512, l = w >> 3, j = w & 7;
    int c = l & 15, g = l >> 4;
    int k = kf * 32 + g * 8 + j, nn = tt * 16 + c;
    W2p[u] = f2b(W2[k * 192 + nn]);
  } else {
    int i = (t - 184320) * 4;
    if (i + 3 < gtotal) {
      float4 v = *(const float4*)(gW + i);
      ushort4 o;
      o.x = f2b(v.x); o.y = f2b(v.y); o.z = f2b(v.z); o.w = f2b(v.w);
      *(ushort4*)(gwb + i) = o;
    }
  }
}

// ---------------- gc1: weighted SPMM + bias + relu + l2norm (unroll-4) ----------------

__global__ __launch_bounds__(256) void k_gc1(const int* __restrict__ rp, const int2* __restrict__ cv,
                                             const unsigned short* __restrict__ Wb,
                                             const float* __restrict__ b, unsigned short* __restrict__ out, int n) {
  int gw = (blockIdx.x * 256 + threadIdx.x) >> 6;
  int l = threadIdx.x & 63;
  if (gw >= n) return;
  int s = rp[gw], e = rp[gw + 1];
  bool act = l < 48;
  float a0 = 0.f, a1 = 0.f, b0 = 0.f, b1 = 0.f, c0 = 0.f, c1 = 0.f, d0 = 0.f, d1 = 0.f;
  int i = s;
  for (; i + 3 < e; i += 4) {
    int2 q0 = cv[i], q1 = cv[i + 1], q2 = cv[i + 2], q3 = cv[i + 3];
    if (act) {
      unsigned w0 = *(const unsigned*)(Wb + (size_t)q0.x * NH + 2 * l);
      unsigned w1 = *(const unsigned*)(Wb + (size_t)q1.x * NH + 2 * l);
      unsigned w2 = *(const unsigned*)(Wb + (size_t)q2.x * NH + 2 * l);
      unsigned w3 = *(const unsigned*)(Wb + (size_t)q3.x * NH + 2 * l);
      float v0 = __int_as_float(q0.y), v1 = __int_as_float(q1.y);
      float v2 = __int_as_float(q2.y), v3 = __int_as_float(q3.y);
      a0 = fmaf(v0, blo(w0), a0); a1 = fmaf(v0, bhi(w0), a1);
      b0 = fmaf(v1, blo(w1), b0); b1 = fmaf(v1, bhi(w1), b1);
      c0 = fmaf(v2, blo(w2), c0); c1 = fmaf(v2, bhi(w2), c1);
      d0 = fmaf(v3, blo(w3), d0); d1 = fmaf(v3, bhi(w3), d1);
    }
  }
  for (; i < e; ++i) {
    int2 q0 = cv[i];
    if (act) {
      unsigned w0 = *(const unsigned*)(Wb + (size_t)q0.x * NH + 2 * l);
      float v0 = __int_as_float(q0.y);
      a0 = fmaf(v0, blo(w0), a0); a1 = fmaf(v0, bhi(w0), a1);
    }
  }
  a0 += b0 + c0 + d0; a1 += b1 + c1 + d1;
  if (act) {
    a0 = fmaxf(a0 + b[2 * l], 0.f);
    a1 = fmaxf(a1 + b[2 * l + 1], 0.f);
  } else { a0 = a1 = 0.f; }
  float ss = a0 * a0 + a1 * a1;
#pragma unroll
  for (int o = 1; o < 64; o <<= 1) ss += __shfl_xor(ss, o);
  float sc = 1.f / fmaxf(sqrtf(ss), 1e-12f);
  if (act) {
    unsigned pk = ((unsigned)f2b(a1 * sc) << 16) | f2b(a0 * sc);
    ((unsigned*)out)[(size_t)gw * 48 + l] = pk;
  }
}

// ---------------- mean aggregation (unroll-4) — shared branch input ----------------

__global__ __launch_bounds__(256) void k_agg(const int* __restrict__ rp, const int* __restrict__ csrc,
                                             const unsigned short* __restrict__ X,
                                             unsigned short* __restrict__ out, int n) {
  int gw = (blockIdx.x * 256 + threadIdx.x) >> 6;
  int l = threadIdx.x & 63;
  if (gw >= n) return;
  int s = rp[gw], e = rp[gw + 1];
  bool act = l < 48;
  float a0 = 0.f, a1 = 0.f, b0 = 0.f, b1 = 0.f, c0 = 0.f, c1 = 0.f, d0 = 0.f, d1 = 0.f;
  int i = s;
  for (; i + 3 < e; i += 4) {
    int s0 = csrc[i], s1 = csrc[i + 1], s2 = csrc[i + 2], s3 = csrc[i + 3];
    if (act) {
      unsigned w0 = *(const unsigned*)(X + (size_t)s0 * NH + 2 * l);
      unsigned w1 = *(const unsigned*)(X + (size_t)s1 * NH + 2 * l);
      unsigned w2 = *(const unsigned*)(X + (size_t)s2 * NH + 2 * l);
      unsigned w3 = *(const unsigned*)(X + (size_t)s3 * NH + 2 * l);
      a0 += blo(w0); a1 += bhi(w0);
      b0 += blo(w1); b1 += bhi(w1);
      c0 += blo(w2); c1 += bhi(w2);
      d0 += blo(w3); d1 += bhi(w3);
    }
  }
  for (; i < e; ++i) {
    int s0 = csrc[i];
    if (act) {
      unsigned w0 = *(const unsigned*)(X + (size_t)s0 * NH + 2 * l);
      a0 += blo(w0); a1 += bhi(w0);
    }
  }
  a0 += b0 + c0 + d0; a1 += b1 + c1 + d1;
  float inv = 1.f / fmaxf((float)(e - s), 1.f);
  if (act) {
    unsigned pk = ((unsigned)f2b(a1 * inv) << 16) | f2b(a0 * inv);
    ((unsigned*)out)[(size_t)gw * 48 + l] = pk;
  }
}

// ---------------- trunk fused agg+SAGE, T=1, LDS-staged weights ----------------

template <int EPI>
__global__ __launch_bounds__(256) void k_sageagg(const int* __restrict__ rp, const int* __restrict__ csrc,
                                                 const unsigned short* __restrict__ X,
                                                 const unsigned short* __restrict__ Wlp,
                                                 const unsigned short* __restrict__ Wrp,
                                                 const float* __restrict__ bias,
                                                 unsigned short* __restrict__ Y, int n) {
  __shared__ __align__(16) unsigned short sw[18432];
  int tid = threadIdx.x;
  int l = tid & 63;
  int m0 = (blockIdx.x * 4 + (tid >> 6)) * 16;
  int c = l & 15, g = l >> 4;

  stage(sw, Wlp, 9216, tid, 256);
  stage(sw + 9216, Wrp, 9216, tid, 256);
  __syncthreads();

  int nd = min(m0 + c, n - 1);
  int s = rp[nd], e = rp[nd + 1];

  float aa[3][8], bb[3][8];
#pragma unroll
  for (int kf = 0; kf < 3; ++kf)
#pragma unroll
    for (int j = 0; j < 8; ++j) { aa[kf][j] = 0.f; bb[kf][j] = 0.f; }

  const unsigned short* Xg = X + g * 8;
  int i = s;
  for (; i + 1 < e; i += 2) {
    const unsigned short* xr0 = Xg + (size_t)csrc[i] * NH;
    const unsigned short* xr1 = Xg + (size_t)csrc[i + 1] * NH;
    short8 a0 = *(const short8*)(xr0);
    short8 a1 = *(const short8*)(xr0 + 32);
    short8 a2 = *(const short8*)(xr0 + 64);
    short8 b0 = *(const short8*)(xr1);
    short8 b1 = *(const short8*)(xr1 + 32);
    short8 b2 = *(const short8*)(xr1 + 64);
#pragma unroll
    for (int j = 0; j < 8; ++j) {
      aa[0][j] += b2f(a0[j]); aa[1][j] += b2f(a1[j]); aa[2][j] += b2f(a2[j]);
      bb[0][j] += b2f(b0[j]); bb[1][j] += b2f(b1[j]); bb[2][j] += b2f(b2[j]);
    }
  }
  if (i < e) {
    const unsigned short* xr0 = Xg + (size_t)csrc[i] * NH;
    short8 a0 = *(const short8*)(xr0);
    short8 a1 = *(const short8*)(xr0 + 32);
    short8 a2 = *(const short8*)(xr0 + 64);
#pragma unroll
    for (int j = 0; j < 8; ++j) {
      aa[0][j] += b2f(a0[j]); aa[1][j] += b2f(a1[j]); aa[2][j] += b2f(a2[j]);
    }
  }
  float inv = 1.f / fmaxf((float)(e - s), 1.f);
  short8 af[3];
#pragma unroll
  for (int kf = 0; kf < 3; ++kf)
#pragma unroll
    for (int j = 0; j < 8; ++j) af[kf][j] = (short)f2b((aa[kf][j] + bb[kf][j]) * inv);

  size_t aoff = (size_t)nd * NH + g * 8;
  short8 xf[3];
#pragma unroll
  for (int kf = 0; kf < 3; ++kf) xf[kf] = *(const short8*)(X + aoff + kf * 32);

  f32x4 acc[6];
#pragma unroll
  for (int t = 0; t < 6; ++t) acc[t] = (f32x4){0.f, 0.f, 0.f, 0.f};
#pragma unroll
  for (int kf = 0; kf < 3; ++kf) {
#pragma unroll
    for (int t = 0; t < 6; ++t) {
      short8 wlf = WFRAG(sw, t * 3 + kf);
      acc[t] = MFMA(wlf, af[kf], acc[t]);
    }
#pragma unroll
    for (int t = 0; t < 6; ++t) {
      short8 wrf = WFRAG(sw + 9216, t * 3 + kf);
      acc[t] = MFMA(wrf, xf[kf], acc[t]);
    }
  }

  float v[6][4];
  float ss = 0.f;
#pragma unroll
  for (int t = 0; t < 6; ++t) {
    float4 bv = *(const float4*)(bias + t * 16 + g * 4);
#pragma unroll
    for (int r = 0; r < 4; ++r) {
      float x = fmaxf(acc[t][r] + ((const float*)&bv)[r], 0.f);
      v[t][r] = x;
      ss = fmaf(x, x, ss);
    }
  }
  if (EPI == 0) {
    ss += __shfl_xor(ss, 16);
    ss += __shfl_xor(ss, 32);
    float sc = 1.f / fmaxf(sqrtf(ss), 1e-12f);
#pragma unroll
    for (int t = 0; t < 6; ++t)
#pragma unroll
      for (int r = 0; r < 4; ++r) v[t][r] *= sc;
  }
  if (m0 + c < n) {
    unsigned short* yr = Y + (size_t)(m0 + c) * NH;
#pragma unroll
    for (int t = 0; t < 6; ++t)
      *(uint2*)(yr + t * 16 + g * 4) = make_uint2(cvt_pk(v[t][0], v[t][1]), cvt_pk(v[t][2], v[t][3]));
  }
}

// ---------------- fused 3-layer MLP, T=2, LDS-staged weights: score += mlp(X) (final layer) ----------------

__global__ __launch_bounds__(256) void k_mlp(const unsigned short* __restrict__ X,
                                             const unsigned short* __restrict__ W1p, const float* __restrict__ b1,
                                             const unsigned short* __restrict__ W2p, const float* __restrict__ b2,
                                             const float* __restrict__ W3, const float* __restrict__ b3,
                                             float* __restrict__ score, int n) {
  __shared__ __align__(16) unsigned short sw[18432];
  int tid = threadIdx.x;
  int l = tid & 63;
  int m0 = (blockIdx.x * 4 + (tid >> 6)) * 32;
  int c = l & 15, g = l >> 4;
  int srcA = c + ((g & 1) << 5), srcB = srcA + 16, hi = g >> 1;
  int rA = min(m0 + c, n - 1), rB = min(m0 + 16 + c, n - 1);

  stage(sw, W1p, 18432, tid, 256);

  short8 xf[2][3];
#pragma unroll
  for (int kf = 0; kf < 3; ++kf) {
    xf[0][kf] = *(const short8*)(X + (size_t)rA * NH + kf * 32 + g * 8);
    xf[1][kf] = *(const short8*)(X + (size_t)rB * NH + kf * 32 + g * 8);
  }
  __syncthreads();

  unsigned pk1[2][12][2];
#pragma unroll
  for (int t = 0; t < 12; ++t) {
    f32x4 a0 = (f32x4){0.f, 0.f, 0.f, 0.f};
    f32x4 a1 = (f32x4){0.f, 0.f, 0.f, 0.f};
#pragma unroll
    for (int kf = 0; kf < 3; ++kf) {
      short8 wf = WFRAG(sw, t * 3 + kf);
      a0 = MFMA(wf, xf[0][kf], a0);
      a1 = MFMA(wf, xf[1][kf], a1);
    }
    float4 bv = *(const float4*)(b1 + t * 16 + g * 4);
    pk1[0][t][0] = cvt_pk(fmaxf(a0[0] + bv.x, 0.f), fmaxf(a0[1] + bv.y, 0.f));
    pk1[0][t][1] = cvt_pk(fmaxf(a0[2] + bv.z, 0.f), fmaxf(a0[3] + bv.w, 0.f));
    pk1[1][t][0] = cvt_pk(fmaxf(a1[0] + bv.x, 0.f), fmaxf(a1[1] + bv.y, 0.f));
    pk1[1][t][1] = cvt_pk(fmaxf(a1[2] + bv.z, 0.f), fmaxf(a1[3] + bv.w, 0.f));
  }

  short8 af2[2][6];
#pragma unroll
  for (int kf = 0; kf < 6; ++kf) {
    af2[0][kf] = xchg(pk1[0][2 * kf][0], pk1[0][2 * kf][1], pk1[0][2 * kf + 1][0], pk1[0][2 * kf + 1][1], srcA, srcB, hi);
    af2[1][kf] = xchg(pk1[1][2 * kf][0], pk1[1][2 * kf][1], pk1[1][2 * kf + 1][0], pk1[1][2 * kf + 1][1], srcA, srcB, hi);
  }

  float sv0 = 0.f, sv1 = 0.f;
#pragma unroll
  for (int h = 0; h < 2; ++h) {
    __syncthreads();
    stage(sw, W2p + h * 18432, 18432, tid, 256);
    __syncthreads();
#pragma unroll
    for (int tt = 0; tt < 6; ++tt) {
      int t = h * 6 + tt;
      f32x4 a0 = (f32x4){0.f, 0.f, 0.f, 0.f};
      f32x4 a1 = (f32x4){0.f, 0.f, 0.f, 0.f};
#pragma unroll
      for (int kf = 0; kf < 6; ++kf) {
        short8 wf = WFRAG(sw, tt * 6 + kf);
        a0 = MFMA(wf, af2[0][kf], a0);
        a1 = MFMA(wf, af2[1][kf], a1);
      }
      float4 bv = *(const float4*)(b2 + t * 16 + g * 4);
      float4 wv3 = *(const float4*)(W3 + t * 16 + g * 4);
#pragma unroll
      for (int r = 0; r < 4; ++r) {
        sv0 = fmaf(fmaxf(a0[r] + ((const float*)&bv)[r], 0.f), ((const float*)&wv3)[r], sv0);
        sv1 = fmaf(fmaxf(a1[r] + ((const float*)&bv)[r], 0.f), ((const float*)&wv3)[r], sv1);
      }
    }
  }
  sv0 += __shfl_xor(sv0, 16); sv0 += __shfl_xor(sv0, 32);
  sv1 += __shfl_xor(sv1, 16); sv1 += __shfl_xor(sv1, 32);
  if (g == 0) {
    float b3v = b3[0];
    if (m0 + c < n) score[m0 + c] += sv0 + b3v;
    if (m0 + 16 + c < n) score[m0 + 16 + c] += sv1 + b3v;
  }
}

// ---------------- per-branch, 8 waves x T=2, LDS-staged weights ----------------
// bb = blockIdx.x / nblk in [0,6]; bb<6: SAGE(Ag,x21;W[bb]) -> l2norm -> MLP; bb==6: MLP(x21) directly.

__global__ __launch_bounds__(512) void k_branch(const unsigned short* __restrict__ Ag,
                                                const unsigned short* __restrict__ X21,
                                                const unsigned short* __restrict__ Wlp,
                                                const unsigned short* __restrict__ Wrp,
                                                const float* __restrict__ sbl,
                                                const unsigned short* __restrict__ W1p, const float* __restrict__ b1,
                                                const unsigned short* __restrict__ W2p, const float* __restrict__ b2,
                                                const float* __restrict__ W3, const float* __restrict__ b3,
                                                unsigned short* __restrict__ Xb, float* __restrict__ score,
                                                int n, int nblk) {
  __shared__ __align__(16) unsigned short sw[18432];
  int bb = blockIdx.x / nblk;
  int blk = blockIdx.x - bb * nblk;
  int tid = threadIdx.x;
  int l = tid & 63;
  int m0 = (blk * 8 + (tid >> 6)) * 32;
  int c = l & 15, g = l >> 4;
  int srcA = c + ((g & 1) << 5), srcB = srcA + 16, hi = g >> 1;
  int rA = min(m0 + c, n - 1), rB = min(m0 + 16 + c, n - 1);
  size_t aoffA = (size_t)rA * NH + g * 8, aoffB = (size_t)rB * NH + g * 8;

  short8 af1[2][3];

  if (bb < 6) {
    const float* bl = sbl + (size_t)bb * NH;
    stage(sw, Wlp + (size_t)bb * 9216, 9216, tid, 512);
    stage(sw + 9216, Wrp + (size_t)bb * 9216, 9216, tid, 512);

    short8 agf[2][3], xf[2][3];
#pragma unroll
    for (int kf = 0; kf < 3; ++kf) {
      agf[0][kf] = *(const short8*)(Ag + aoffA + kf * 32);
      agf[1][kf] = *(const short8*)(Ag + aoffB + kf * 32);
      xf[0][kf] = *(const short8*)(X21 + aoffA + kf * 32);
      xf[1][kf] = *(const short8*)(X21 + aoffB + kf * 32);
    }
    __syncthreads();

    // ---- SAGE, t-outer ----
    float v[2][6][4];
    float ss0 = 0.f, ss1 = 0.f;
#pragma unroll
    for (int t = 0; t < 6; ++t) {
      f32x4 a0 = (f32x4){0.f, 0.f, 0.f, 0.f};
      f32x4 a1 = (f32x4){0.f, 0.f, 0.f, 0.f};
#pragma unroll
      for (int kf = 0; kf < 3; ++kf) {
        short8 wlf = WFRAG(sw, t * 3 + kf);
        a0 = MFMA(wlf, agf[0][kf], a0);
        a1 = MFMA(wlf, agf[1][kf], a1);
        short8 wrf = WFRAG(sw + 9216, t * 3 + kf);
        a0 = MFMA(wrf, xf[0][kf], a0);
        a1 = MFMA(wrf, xf[1][kf], a1);
      }
      float4 bv = *(const float4*)(bl + t * 16 + g * 4);
#pragma unroll
      for (int r = 0; r < 4; ++r) {
        float x0 = fmaxf(a0[r] + ((const float*)&bv)[r], 0.f);
        float x1 = fmaxf(a1[r] + ((const float*)&bv)[r], 0.f);
        v[0][t][r] = x0; ss0 = fmaf(x0, x0, ss0);
        v[1][t][r] = x1; ss1 = fmaf(x1, x1, ss1);
      }
    }
    ss0 += __shfl_xor(ss0, 16); ss0 += __shfl_xor(ss0, 32);
    ss1 += __shfl_xor(ss1, 16); ss1 += __shfl_xor(ss1, 32);
    float sc0 = 1.f / fmaxf(sqrtf(ss0), 1e-12f);
    float sc1 = 1.f / fmaxf(sqrtf(ss1), 1e-12f);

    unsigned pk[2][6][2];
#pragma unroll
    for (int t = 0; t < 6; ++t) {
      pk[0][t][0] = cvt_pk(v[0][t][0] * sc0, v[0][t][1] * sc0);
      pk[0][t][1] = cvt_pk(v[0][t][2] * sc0, v[0][t][3] * sc0);
      pk[1][t][0] = cvt_pk(v[1][t][0] * sc1, v[1][t][1] * sc1);
      pk[1][t][1] = cvt_pk(v[1][t][2] * sc1, v[1][t][3] * sc1);
    }
    if (bb == 0) {
      if (m0 + c < n) {
        unsigned short* yr = Xb + (size_t)(m0 + c) * NH;
#pragma unroll
        for (int t = 0; t < 6; ++t) *(uint2*)(yr + t * 16 + g * 4) = make_uint2(pk[0][t][0], pk[0][t][1]);
      }
      if (m0 + 16 + c < n) {
        unsigned short* yr = Xb + (size_t)(m0 + 16 + c) * NH;
#pragma unroll
        for (int t = 0; t < 6; ++t) *(uint2*)(yr + t * 16 + g * 4) = make_uint2(pk[1][t][0], pk[1][t][1]);
      }
    }

    __syncthreads();  // done reading Wl/Wr
    stage(sw, W1p, 18432, tid, 512);
#pragma unroll
    for (int kf = 0; kf < 3; ++kf) {
      af1[0][kf] = xchg(pk[0][2 * kf][0], pk[0][2 * kf][1], pk[0][2 * kf + 1][0], pk[0][2 * kf + 1][1], srcA, srcB, hi);
      af1[1][kf] = xchg(pk[1][2 * kf][0], pk[1][2 * kf][1], pk[1][2 * kf + 1][0], pk[1][2 * kf + 1][1], srcA, srcB, hi);
    }
    __syncthreads();  // W1 ready
  } else {
    // bb == 6: plain MLP on x2_1 — A-fragments are the raw rows
#pragma unroll
    for (int kf = 0; kf < 3; ++kf) {
      af1[0][kf] = *(const short8*)(X21 + aoffA + kf * 32);
      af1[1][kf] = *(const short8*)(X21 + aoffB + kf * 32);
    }
    stage(sw, W1p, 18432, tid, 512);
    __syncthreads();  // W1 ready
  }

  // ---- MLP1, t-outer ----
  unsigned pk1[2][12][2];
#pragma unroll
  for (int t = 0; t < 12; ++t) {
    f32x4 a0 = (f32x4){0.f, 0.f, 0.f, 0.f};
    f32x4 a1 = (f32x4){0.f, 0.f, 0.f, 0.f};
#pragma unroll
    for (int kf = 0; kf < 3; ++kf) {
      short8 wf = WFRAG(sw, t * 3 + kf);
      a0 = MFMA(wf, af1[0][kf], a0);
      a1 = MFMA(wf, af1[1][kf], a1);
    }
    float4 bv = *(const float4*)(b1 + t * 16 + g * 4);
    pk1[0][t][0] = cvt_pk(fmaxf(a0[0] + bv.x, 0.f), fmaxf(a0[1] + bv.y, 0.f));
    pk1[0][t][1] = cvt_pk(fmaxf(a0[2] + bv.z, 0.f), fmaxf(a0[3] + bv.w, 0.f));
    pk1[1][t][0] = cvt_pk(fmaxf(a1[0] + bv.x, 0.f), fmaxf(a1[1] + bv.y, 0.f));
    pk1[1][t][1] = cvt_pk(fmaxf(a1[2] + bv.z, 0.f), fmaxf(a1[3] + bv.w, 0.f));
  }

  // ---- MLP2+3, t-outer, W2 staged in two halves ----
  short8 af2[2][6];
#pragma unroll
  for (int kf = 0; kf < 6; ++kf) {
    af2[0][kf] = xchg(pk1[0][2 * kf][0], pk1[0][2 * kf][1], pk1[0][2 * kf + 1][0], pk1[0][2 * kf + 1][1], srcA, srcB, hi);
    af2[1][kf] = xchg(pk1[1][2 * kf][0], pk1[1][2 * kf][1], pk1[1][2 * kf + 1][0], pk1[1][2 * kf + 1][1], srcA, srcB, hi);
  }
  float sv0 = 0.f, sv1 = 0.f;
#pragma unroll
  for (int h = 0; h < 2; ++h) {
    __syncthreads();
    stage(sw, W2p + h * 18432, 18432, tid, 512);
    __syncthreads();
#pragma unroll
    for (int tt = 0; tt < 6; ++tt) {
      int t = h * 6 + tt;
      f32x4 a0 = (f32x4){0.f, 0.f, 0.f, 0.f};
      f32x4 a1 = (f32x4){0.f, 0.f, 0.f, 0.f};
#pragma unroll
      for (int kf = 0; kf < 6; ++kf) {
        short8 wf = WFRAG(sw, tt * 6 + kf);
        a0 = MFMA(wf, af2[0][kf], a0);
        a1 = MFMA(wf, af2[1][kf], a1);
      }
      float4 bv = *(const float4*)(b2 + t * 16 + g * 4);
      float4 wv3 = *(const float4*)(W3 + t * 16 + g * 4);
#pragma unroll
      for (int r = 0; r < 4; ++r) {
        sv0 = fmaf(fmaxf(a0[r] + ((const float*)&bv)[r], 0.f), ((const float*)&wv3)[r], sv0);
        sv1 = fmaf(fmaxf(a1[r] + ((const float*)&bv)[r], 0.f), ((const float*)&wv3)[r], sv1);
      }
    }
  }
  sv0 += __shfl_xor(sv0, 16); sv0 += __shfl_xor(sv0, 32);
  sv1 += __shfl_xor(sv1, 16); sv1 += __shfl_xor(sv1, 32);
  if (g == 0) {
    float b3v = b3[0];
    if (m0 + c < n) atomicAdd(&score[m0 + c], sv0 + b3v);
    if (m0 + 16 + c < n) atomicAdd(&score[m0 + 16 + c], sv1 + b3v);
  }
}

// ---------------- host ----------------

extern "C" void kernel_launch(void* const* d_in, const int* in_sizes, int n_in,
                              void* d_out, int out_size, void* d_ws, size_t ws_size,
                              hipStream_t stream) {
  const int* ei1 = (const int*)d_in[0];
  const float* ev1 = (const float*)d_in[1];
  const int* ei2 = (const int*)d_in[2];
  const float* gW = (const float*)d_in[3];
  const float* gb = (const float*)d_in[4];
  const float* sWl = (const float*)d_in[5];
  const float* sbl = (const float*)d_in[6];
  const float* sWr = (const float*)d_in[7];
  const float* W1 = (const float*)d_in[8];
  const float* b1 = (const float*)d_in[9];
  const float* W2 = (const float*)d_in[10];
  const float* b2 = (const float*)d_in[11];
  const float* W3 = (const float*)d_in[12];
  const float* b3 = (const float*)d_in[13];
  float* score = (float*)d_out;

  const int E = in_sizes[0] / 2;
  const int n = in_sizes[3] / NH;

  const int* d1 = ei1;      // edge_index1[0] = dst
  const int* s1 = ei1 + E;  // edge_index1[1] = src
  const int* s2 = ei2;      // edge_index2[0] = src
  const int* d2 = ei2 + E;  // edge_index2[1] = dst

  char* w = (char*)d_ws;
  auto alloc = [&](size_t bytes) {
    char* p = w;
    w += (bytes + 255) & ~(size_t)255;
    return p;
  };
  int* cnt1 = (int*)alloc((size_t)n * 4);
  int* cnt2 = (int*)alloc((size_t)n * 4);
  int* cur1 = (int*)alloc((size_t)n * 4);
  int* cur2 = (int*)alloc((size_t)n * 4);
  int* rp1 = (int*)alloc((size_t)(n + 1) * 4);
  int* rp2 = (int*)alloc((size_t)(n + 1) * 4);
  int* bs = (int*)alloc(128 * 4);
  int2* c1sv = (int2*)alloc((size_t)E * 8);
  int* c2s = (int*)alloc((size_t)E * 4);
  unsigned short* gwb = (unsigned short*)alloc((size_t)n * NH * 2);
  unsigned short* wlp = (unsigned short*)alloc((size_t)7 * NH * NH * 2);
  unsigned short* wrp = (unsigned short*)alloc((size_t)7 * NH * NH * 2);
  unsigned short* w1p = (unsigned short*)alloc((size_t)NH * NH2 * 2);
  unsigned short* w2p = (unsigned short*)alloc((size_t)NH2 * NH2 * 2);
  unsigned short* x21 = (unsigned short*)alloc((size_t)n * NH * 2);
  unsigned short* Ag = (unsigned short*)alloc((size_t)n * NH * 2);
  unsigned short* xb = (unsigned short*)alloc((size_t)n * NH * 2);
  unsigned short* tb = (unsigned short*)alloc((size_t)n * NH * 2);

  // zero cnt1+cnt2 (contiguous region) + score
  size_t zbytes = (size_t)((char*)cur1 - (char*)cnt1) + (size_t)n * 4;
  hipMemsetAsync(cnt1, 0, zbytes, stream);
  hipMemsetAsync(score, 0, (size_t)n * 4, stream);

  int eb = (E + 255) / 256;
  int nb4 = (n + 3) / 4;          // wave-per-node kernels
  int sblk = (n + 63) / 64;       // T=1 staged agg+sage: 4 waves x 16 nodes
  int gblk = (n + 127) / 128;     // T=2 4-wave MFMA kernel (final mlp)
  int nblk = (n + 255) / 256;     // 8-wave T=2 branch blocks
  int psize = (n + 7) / 8;        // dst-partition size
  int nb1024 = (n + 1023) / 1024; // hierarchical scan blocks per segment
  int gtotal = n * NH;
  int prep_threads = 184320 + gtotal / 4;

  k_count<<<eb * 8, 256, 0, stream>>>(d1, d2, cnt1, cnt2, E, psize);
  if (nb1024 <= 64) {
    k_scanA<<<dim3(nb1024, 2), 256, 0, stream>>>(cnt1, cnt2, bs, n);
    k_scanB<<<1, 128, 0, stream>>>(bs, rp1, rp2, nb1024, n);
    k_scanC<<<dim3(nb1024, 2), 256, 0, stream>>>(cnt1, cnt2, bs, rp1, cur1, rp2, cur2, n);
  } else {
    k_scan<<<1, 1024, 0, stream>>>(cnt1, rp1, cur1, n);
    k_scan<<<1, 1024, 0, stream>>>(cnt2, rp2, cur2, n);
  }
  k_scatter<<<eb * 8, 256, 0, stream>>>(d1, s1, ev1, cur1, c1sv, s2, d2, cur2, c2s, E, psize);

  k_prep<<<(prep_threads + 255) / 256, 256, 0, stream>>>(sWl, sWr, W1, W2, gW,
                                                         wlp, wrp, w1p, w2p, gwb, gtotal);

  // x2_1 = l2norm(relu(spmm(adj1, gc1_W) + gc1_b))
  k_gc1<<<nb4, 256, 0, stream>>>(rp1, c1sv, gwb, gb, x21, n);

  // Ag = mean-agg(x2_1) — shared by all 6 score branches (incl. trunk layer 0)
  k_agg<<<nb4, 256, 0, stream>>>(rp2, c2s, x21, Ag, n);

  // 7 grid slices: 6 score branches (slice 0 emits xb) + slice 6 = mlp(x2_1)
  k_branch<<<7 * nblk, 512, 0, stream>>>(Ag, x21, wlp, wrp, sbl, w1p, b1, w2p, b2, W3, b3,
                                         xb, score, n, nblk);

  // trunk layers 1..5 (fused agg+sage, T=1 staged)
  unsigned short* xc = xb;
  unsigned short* xn = tb;
  for (int i = 1; i < 6; ++i) {
    k_sageagg<0><<<sblk, 256, 0, stream>>>(rp2, c2s, xc, wlp + (size_t)i * 9216,
                                           wrp + (size_t)i * 9216, sbl + (size_t)i * NH, xn, n);
    unsigned short* tmp = xc; xc = xn; xn = tmp;
  }

  // last layer: relu only, then final mlp
  k_sageagg<1><<<sblk, 256, 0, stream>>>(rp2, c2s, xc, wlp + (size_t)6 * 9216,
                                         wrp + (size_t)6 * 9216, sbl + (size_t)6 * NH, xn, n);
  k_mlp<<<gblk, 256, 0, stream>>>(xn, w1p, b1, w2p, b2, W3, b3, score, n);

  (void)n_in; (void)out_size; (void)ws_size;
}